// Round 3
// baseline (1538.831 us; speedup 1.0000x reference)
//
#include <hip/hip_runtime.h>
#include <hip/hip_bf16.h>

#define NN 50000
#define EE 850000
#define NBLK_SCAN 98  // ceil(50000/512)

typedef unsigned short u16;

__device__ __forceinline__ float bf2f(u16 u) {
    union { unsigned int i; float f; } v; v.i = ((unsigned int)u) << 16; return v.f;
}
__device__ __forceinline__ u16 f2bf(float f) {
    __hip_bfloat16 h = __float2bfloat16(f);
    return *reinterpret_cast<u16*>(&h);
}

// dual-dtype input loads: f32m ? float : bf16
__device__ __forceinline__ float ld1(const void* X, size_t i, bool f32m) {
    return f32m ? ((const float*)X)[i] : bf2f(((const u16*)X)[i]);
}
__device__ __forceinline__ void load4(const void* X, size_t g, bool f32m, float o[4]) {
    if (f32m) {
        float4 v = ((const float4*)X)[g];
        o[0] = v.x; o[1] = v.y; o[2] = v.z; o[3] = v.w;
    } else {
        ushort4 v = ((const ushort4*)X)[g];
        o[0] = bf2f(v.x); o[1] = bf2f(v.y); o[2] = bf2f(v.z); o[3] = bf2f(v.w);
    }
}
__device__ __forceinline__ void load2(const void* X, size_t g, bool f32m, float o[2]) {
    if (f32m) {
        float2 v = ((const float2*)X)[g];
        o[0] = v.x; o[1] = v.y;
    } else {
        ushort2 v = ((const ushort2*)X)[g];
        o[0] = bf2f(v.x); o[1] = bf2f(v.y);
    }
}

// ---- dtype detector: bf16-real data has sane exponent fields; f32 data
// reinterpreted as u16 has ~36% wild exponents among sampled halves ----
__global__ void k_detect(const u16* __restrict__ hh, int* __restrict__ flag) {
    __shared__ int sm[256];
    int t = threadIdx.x;
    int c = 0;
    for (int i = 0; i < 16; ++i) {
        u16 u = hh[t * 16 + i];
        int e = (u >> 7) & 0xFF;
        if (e != 0 && (e < 90 || e > 160)) ++c;
    }
    sm[t] = c;
    __syncthreads();
    for (int s = 128; s > 0; s >>= 1) {
        if (t < s) sm[t] += sm[t + s];
        __syncthreads();
    }
    if (t == 0) *flag = (sm[0] > 200) ? 1 : 0;
}

// ---- attention projection vectors: wl[k][h] = sum_d W[k][h*D+d] * a[h][d] ----
__global__ void k_attn_vecs(const void* __restrict__ W1s, const void* __restrict__ al1,
                            const void* __restrict__ W1d, const void* __restrict__ ar1,
                            const void* __restrict__ W2s, const void* __restrict__ al2,
                            const void* __restrict__ W2d, const void* __restrict__ ar2,
                            float* __restrict__ wl1, float* __restrict__ wr1,
                            float* __restrict__ wl2, float* __restrict__ wr2,
                            const int* __restrict__ mode) {
    bool f32m = (*mode) != 0;
    int id = blockIdx.x * 256 + threadIdx.x;  // 0..4095
    int which = id >> 10;
    int rem = id & 1023;
    int k = rem >> 2, h = rem & 3;
    float s = 0.f;
    if (which == 0) {
        for (int d = 0; d < 64; ++d) s += ld1(W1s, k * 256 + h * 64 + d, f32m) * ld1(al1, h * 64 + d, f32m);
        wl1[k * 4 + h] = s;
    } else if (which == 1) {
        for (int d = 0; d < 64; ++d) s += ld1(W1d, k * 256 + h * 64 + d, f32m) * ld1(ar1, h * 64 + d, f32m);
        wr1[k * 4 + h] = s;
    } else if (which == 2) {
        for (int d = 0; d < 32; ++d) s += ld1(W2s, k * 128 + h * 32 + d, f32m) * ld1(al2, h * 32 + d, f32m);
        wl2[k * 4 + h] = s;
    } else {
        for (int d = 0; d < 32; ++d) s += ld1(W2d, k * 128 + h * 32 + d, f32m) * ld1(ar2, h * 32 + d, f32m);
        wr2[k * 4 + h] = s;
    }
}

// ---- CSR build ----
__global__ void k_deg(const int* __restrict__ dst, int* __restrict__ deg) {
    int e = blockIdx.x * 256 + threadIdx.x;
    if (e < EE) atomicAdd(&deg[dst[e]], 1);
}

__global__ void k_scan1(const int* __restrict__ deg, int* __restrict__ rowptr,
                        int* __restrict__ bsum) {
    __shared__ int sm[512];
    int t = threadIdx.x;
    int i = blockIdx.x * 512 + t;
    int v = (i < NN) ? deg[i] : 0;
    int x = v;
    sm[t] = x;
    __syncthreads();
    for (int off = 1; off < 512; off <<= 1) {
        int y = (t >= off) ? sm[t - off] : 0;
        __syncthreads();
        x += y;
        sm[t] = x;
        __syncthreads();
    }
    if (i < NN) rowptr[i] = x - v;  // exclusive within block
    if (t == 511) bsum[blockIdx.x] = x;
}

__global__ void k_scan2(const int* __restrict__ bsum, int* __restrict__ boff) {
    if (threadIdx.x == 0) {
        int run = 0;
        for (int i = 0; i < NBLK_SCAN; ++i) { boff[i] = run; run += bsum[i]; }
    }
}

__global__ void k_scan3(int* __restrict__ rowptr, const int* __restrict__ boff,
                        int* __restrict__ cursor) {
    int i = blockIdx.x * 256 + threadIdx.x;
    if (i < NN) {
        int r = rowptr[i] + boff[i >> 9];
        rowptr[i] = r;
        cursor[i] = r;
        if (i == 0) rowptr[NN] = EE;
    }
}

__global__ void k_scatter(const int* __restrict__ src, const int* __restrict__ dst,
                          int* __restrict__ cursor, int* __restrict__ csrc) {
    int e = blockIdx.x * 256 + threadIdx.x;
    if (e < EE) {
        int d = dst[e];
        int slot = atomicAdd(&cursor[d], 1);
        csrc[slot] = src[e];
    }
}

// ---- el/er: [N][4] = X[N][256] @ wl/wr[256][4], one wave per node ----
__global__ void k_eler(const void* __restrict__ X, int xdual,
                       const float* __restrict__ wl, const float* __restrict__ wr,
                       float* __restrict__ el, float* __restrict__ er,
                       const int* __restrict__ mode) {
    bool f32m = xdual && ((*mode) != 0);
    int wave = threadIdx.x >> 6, lane = threadIdx.x & 63;
    int node = blockIdx.x * 4 + wave;
    float a[4];
    load4(X, (size_t)node * 64 + lane, f32m, a);
    float accl[4] = {0, 0, 0, 0}, accr[4] = {0, 0, 0, 0};
    int k0 = lane * 4;
#pragma unroll
    for (int j = 0; j < 4; ++j) {
        float4 wlv = ((const float4*)wl)[k0 + j];
        float4 wrv = ((const float4*)wr)[k0 + j];
        accl[0] += a[j] * wlv.x; accl[1] += a[j] * wlv.y;
        accl[2] += a[j] * wlv.z; accl[3] += a[j] * wlv.w;
        accr[0] += a[j] * wrv.x; accr[1] += a[j] * wrv.y;
        accr[2] += a[j] * wrv.z; accr[3] += a[j] * wrv.w;
    }
#pragma unroll
    for (int off = 32; off > 0; off >>= 1) {
#pragma unroll
        for (int t = 0; t < 4; ++t) {
            accl[t] += __shfl_down(accl[t], off, 64);
            accr[t] += __shfl_down(accr[t], off, 64);
        }
    }
    if (lane == 0) {
#pragma unroll
        for (int t = 0; t < 4; ++t) {
            el[node * 4 + t] = accl[t];
            er[node * 4 + t] = accr[t];
        }
    }
}

// ---- GEMM: C[M][NC] bf16 = A[M][256] @ B[256][NC]; wave-per-row ----
template <int NC>
__global__ void k_gemm(const void* __restrict__ A, int aDual,
                       const void* __restrict__ B, u16* __restrict__ C,
                       const int* __restrict__ mode) {
    bool f32 = (*mode) != 0;
    bool af32 = aDual && f32;
    constexpr int NV = NC / 64;
    __shared__ float arow[4][256];
    int wave = threadIdx.x >> 6, lane = threadIdx.x & 63;
    int m = blockIdx.x * 4 + wave;
    float av4[4];
    load4(A, (size_t)m * 64 + lane, af32, av4);
    arow[wave][lane * 4 + 0] = av4[0];
    arow[wave][lane * 4 + 1] = av4[1];
    arow[wave][lane * 4 + 2] = av4[2];
    arow[wave][lane * 4 + 3] = av4[3];
    __syncthreads();
    float acc[NV];
#pragma unroll
    for (int j = 0; j < NV; ++j) acc[j] = 0.f;
#pragma unroll 8
    for (int k = 0; k < 256; ++k) {
        float av = arow[wave][k];
        if constexpr (NV == 4) {
            float bv[4];
            load4(B, (size_t)k * 64 + lane, f32, bv);
            acc[0] += av * bv[0];
            acc[1] += av * bv[1];
            acc[2] += av * bv[2];
            acc[3] += av * bv[3];
        } else {
            float bv[2];
            load2(B, (size_t)k * 64 + lane, f32, bv);
            acc[0] += av * bv[0];
            acc[1] += av * bv[1];
        }
    }
    u16* crow = C + (size_t)m * NC + lane * NV;
#pragma unroll
    for (int j = 0; j < NV; ++j) crow[j] = f2bf(acc[j]);
}

// ---- layer-1 aggregation: wave per node, online softmax, D=64, lane=dim ----
__global__ void k_agg1(const int* __restrict__ rowptr, const int* __restrict__ csrc,
                       const float* __restrict__ el, const float* __restrict__ er,
                       const u16* __restrict__ fs, const void* __restrict__ h_in,
                       u16* __restrict__ h1, const int* __restrict__ mode) {
    bool f32m = (*mode) != 0;
    int wave = threadIdx.x >> 6, lane = threadIdx.x & 63;
    int node = blockIdx.x * 4 + wave;
    float4 e4r = ((const float4*)er)[node];
    float ern[4] = {e4r.x, e4r.y, e4r.z, e4r.w};
    float m[4], l[4] = {0, 0, 0, 0}, acc[4] = {0, 0, 0, 0};
#pragma unroll
    for (int t = 0; t < 4; ++t) m[t] = -1.0e30f;
    int beg = rowptr[node], end = rowptr[node + 1];
    for (int p = beg; p < end; ++p) {
        int s = csrc[p];
        float4 e4 = ((const float4*)el)[s];
        float ev[4] = {e4.x + ern[0], e4.y + ern[1], e4.z + ern[2], e4.w + ern[3]};
        const u16* fr = fs + (size_t)s * 256 + lane;
#pragma unroll
        for (int t = 0; t < 4; ++t) {
            float e = ev[t];
            e = e > 0.f ? e : 0.2f * e;
            e = fminf(fmaxf(e, -80.f), 80.f);
            float mn = fmaxf(m[t], e);
            float sc = __expf(m[t] - mn);
            float pw = __expf(e - mn);
            m[t] = mn;
            l[t] = l[t] * sc + pw;
            acc[t] = acc[t] * sc + pw * bf2f(fr[t * 64]);
        }
    }
    size_t base = (size_t)node * 256 + lane;
#pragma unroll
    for (int t = 0; t < 4; ++t) {
        float o = acc[t] / l[t] + ld1(h_in, base + t * 64, f32m);
        o = o > 0.f ? o : __expf(o) - 1.f;  // elu
        h1[base + t * 64] = f2bf(o);
    }
}

// ---- layer-2 aggregation + residual + head-mean: D=32, lane=(hpair,dim) ----
__global__ void k_agg2(const int* __restrict__ rowptr, const int* __restrict__ csrc,
                       const float* __restrict__ el, const float* __restrict__ er,
                       const u16* __restrict__ fs, const u16* __restrict__ res2,
                       void* __restrict__ out, const int* __restrict__ mode) {
    bool f32m = (*mode) != 0;
    int wave = threadIdx.x >> 6, lane = threadIdx.x & 63;
    int node = blockIdx.x * 4 + wave;
    int d = lane & 31, hb = (lane >> 5) * 2;  // heads hb, hb+1
    float4 e4r = ((const float4*)er)[node];
    float ern[2] = {hb == 0 ? e4r.x : e4r.z, hb == 0 ? e4r.y : e4r.w};
    float m[2] = {-1.0e30f, -1.0e30f}, l[2] = {0, 0}, acc[2] = {0, 0};
    int beg = rowptr[node], end = rowptr[node + 1];
    for (int p = beg; p < end; ++p) {
        int s = csrc[p];
        float4 e4 = ((const float4*)el)[s];
        float elv[2] = {hb == 0 ? e4.x : e4.z, hb == 0 ? e4.y : e4.w};
        const u16* fr = fs + (size_t)s * 128 + hb * 32 + d;
#pragma unroll
        for (int t = 0; t < 2; ++t) {
            float e = elv[t] + ern[t];
            e = e > 0.f ? e : 0.2f * e;
            e = fminf(fmaxf(e, -80.f), 80.f);
            float mn = fmaxf(m[t], e);
            float sc = __expf(m[t] - mn);
            float pw = __expf(e - mn);
            m[t] = mn;
            l[t] = l[t] * sc + pw;
            acc[t] = acc[t] * sc + pw * bf2f(fr[t * 32]);
        }
    }
    size_t rb = (size_t)node * 128 + hb * 32 + d;
    float o0 = acc[0] / l[0] + bf2f(res2[rb]);
    float o1 = acc[1] / l[1] + bf2f(res2[rb + 32]);
    float pair = o0 + o1;
    float tot = pair + __shfl_xor(pair, 32, 64);
    if (lane < 32) {
        float v = 0.25f * tot;
        size_t oi = (size_t)node * 32 + d;
        if (f32m) ((float*)out)[oi] = v;
        else ((u16*)out)[oi] = f2bf(v);
    }
}

extern "C" void kernel_launch(void* const* d_in, const int* in_sizes, int n_in,
                              void* d_out, int out_size, void* d_ws, size_t ws_size,
                              hipStream_t stream) {
    // --- input-order detection from size signature (hedge vs non-dict order) ---
    int ih = 0, isrc = 1, idst = 2, iW1s = 3, iW1d = 4, ial1 = 5, iar1 = 6,
        iW2s = 7, iW2d = 8, ial2 = 9, iar2 = 10, iWres = 11;
    if (n_in >= 12 && in_sizes[0] != 12800000) {
        // alphabetical key order: W1_dst,W1_src,W2_dst,W2_src,Wres2,al1,al2,ar1,ar2,dst,h,src
        iW1d = 0; iW1s = 1; iW2d = 2; iW2s = 3; iWres = 4; ial1 = 5; ial2 = 6;
        iar1 = 7; iar2 = 8; idst = 9; ih = 10; isrc = 11;
    }
    const void* h     = d_in[ih];
    const int* src    = (const int*)d_in[isrc];
    const int* dst    = (const int*)d_in[idst];
    const void* W1s   = d_in[iW1s];
    const void* W1d   = d_in[iW1d];
    const void* al1   = d_in[ial1];
    const void* ar1   = d_in[iar1];
    const void* W2s   = d_in[iW2s];
    const void* W2d   = d_in[iW2d];
    const void* al2   = d_in[ial2];
    const void* ar2   = d_in[iar2];
    const void* Wres2 = d_in[iWres];

    char* w = (char*)d_ws;
    size_t off = 0;
    auto alloc = [&](size_t bytes) -> void* {
        void* p = w + off;
        off += (bytes + 255) & ~(size_t)255;
        return p;
    };
    int* mode   = (int*)alloc(256);
    float* wl1 = (float*)alloc(256 * 4 * 4);
    float* wr1 = (float*)alloc(256 * 4 * 4);
    float* wl2 = (float*)alloc(256 * 4 * 4);
    float* wr2 = (float*)alloc(256 * 4 * 4);
    int* deg    = (int*)alloc(NN * 4);
    int* cursor = (int*)alloc(NN * 4);
    int* rowptr = (int*)alloc((NN + 1) * 4);
    int* bsum   = (int*)alloc(NBLK_SCAN * 4);
    int* boff   = (int*)alloc(NBLK_SCAN * 4);
    int* csrc   = (int*)alloc((size_t)EE * 4);
    float* el1  = (float*)alloc((size_t)NN * 4 * 4);
    float* er1  = (float*)alloc((size_t)NN * 4 * 4);
    u16* fs1    = (u16*)alloc((size_t)NN * 256 * 2);   // 25.6 MB
    u16* h1     = (u16*)alloc((size_t)NN * 256 * 2);   // 25.6 MB
    // aliases (stream-ordered reuse of dead buffers):
    float* el2 = el1;
    float* er2 = er1;
    u16* fs2   = fs1;
    u16* res2  = fs1 + (size_t)NN * 128;

    hipMemsetAsync(deg, 0, NN * 4, stream);

    k_detect<<<1, 256, 0, stream>>>((const u16*)h, mode);
    k_attn_vecs<<<16, 256, 0, stream>>>(W1s, al1, W1d, ar1, W2s, al2, W2d, ar2,
                                        wl1, wr1, wl2, wr2, mode);
    k_deg<<<(EE + 255) / 256, 256, 0, stream>>>(dst, deg);
    k_scan1<<<NBLK_SCAN, 512, 0, stream>>>(deg, rowptr, bsum);
    k_scan2<<<1, 64, 0, stream>>>(bsum, boff);
    k_scan3<<<(NN + 255) / 256, 256, 0, stream>>>(rowptr, boff, cursor);
    k_scatter<<<(EE + 255) / 256, 256, 0, stream>>>(src, dst, cursor, csrc);

    // layer 1
    k_eler<<<NN / 4, 256, 0, stream>>>(h, 1, wl1, wr1, el1, er1, mode);
    k_gemm<256><<<NN / 4, 256, 0, stream>>>(h, 1, W1s, fs1, mode);
    k_agg1<<<NN / 4, 256, 0, stream>>>(rowptr, csrc, el1, er1, fs1, h, h1, mode);

    // layer 2 (aliased buffers; all writes stream-ordered after last read)
    k_eler<<<NN / 4, 256, 0, stream>>>(h1, 0, wl2, wr2, el2, er2, mode);
    k_gemm<128><<<NN / 4, 256, 0, stream>>>(h1, 0, W2s, fs2, mode);
    k_gemm<128><<<NN / 4, 256, 0, stream>>>(h1, 0, Wres2, res2, mode);
    k_agg2<<<NN / 4, 256, 0, stream>>>(rowptr, csrc, el2, er2, fs2, res2, d_out, mode);
}

// Round 4
// 532.111 us; speedup vs baseline: 2.8919x; 2.8919x over previous
//
#include <hip/hip_runtime.h>
#include <hip/hip_bf16.h>

#define NN 50000
#define EE 850000
#define NBLK_SCAN 98  // ceil(50000/512)
#define MT 782        // ceil(NN/64)

typedef unsigned short u16;
using short8 = __attribute__((ext_vector_type(8))) short;
using f32x4  = __attribute__((ext_vector_type(4))) float;

__device__ __forceinline__ float bf2f(u16 u) {
    union { unsigned int i; float f; } v; v.i = ((unsigned int)u) << 16; return v.f;
}
__device__ __forceinline__ u16 f2bf(float f) {
    __hip_bfloat16 h = __float2bfloat16(f);
    return *reinterpret_cast<u16*>(&h);
}

// dual-dtype input loads: f32m ? float : bf16
__device__ __forceinline__ float ld1(const void* X, size_t i, bool f32m) {
    return f32m ? ((const float*)X)[i] : bf2f(((const u16*)X)[i]);
}
__device__ __forceinline__ void load4(const void* X, size_t g, bool f32m, float o[4]) {
    if (f32m) {
        float4 v = ((const float4*)X)[g];
        o[0] = v.x; o[1] = v.y; o[2] = v.z; o[3] = v.w;
    } else {
        ushort4 v = ((const ushort4*)X)[g];
        o[0] = bf2f(v.x); o[1] = bf2f(v.y); o[2] = bf2f(v.z); o[3] = bf2f(v.w);
    }
}

// ---- dtype detector (bf16-real vs f32-reinterpreted-as-u16) ----
__global__ void k_detect(const u16* __restrict__ hh, int* __restrict__ flag) {
    __shared__ int sm[256];
    int t = threadIdx.x;
    int c = 0;
    for (int i = 0; i < 16; ++i) {
        u16 u = hh[t * 16 + i];
        int e = (u >> 7) & 0xFF;
        if (e != 0 && (e < 90 || e > 160)) ++c;
    }
    sm[t] = c;
    __syncthreads();
    for (int s = 128; s > 0; s >>= 1) {
        if (t < s) sm[t] += sm[t + s];
        __syncthreads();
    }
    if (t == 0) *flag = (sm[0] > 200) ? 1 : 0;
}

// ---- attention projection vectors: wl[k][h] = sum_d W[k][h*D+d] * a[h][d] ----
__global__ void k_attn_vecs(const void* __restrict__ W1s, const void* __restrict__ al1,
                            const void* __restrict__ W1d, const void* __restrict__ ar1,
                            const void* __restrict__ W2s, const void* __restrict__ al2,
                            const void* __restrict__ W2d, const void* __restrict__ ar2,
                            float* __restrict__ wl1, float* __restrict__ wr1,
                            float* __restrict__ wl2, float* __restrict__ wr2,
                            const int* __restrict__ mode) {
    bool f32m = (*mode) != 0;
    int id = blockIdx.x * 256 + threadIdx.x;  // 0..4095
    int which = id >> 10;
    int rem = id & 1023;
    int k = rem >> 2, h = rem & 3;
    float s = 0.f;
    if (which == 0) {
        for (int d = 0; d < 64; ++d) s += ld1(W1s, k * 256 + h * 64 + d, f32m) * ld1(al1, h * 64 + d, f32m);
        wl1[k * 4 + h] = s;
    } else if (which == 1) {
        for (int d = 0; d < 64; ++d) s += ld1(W1d, k * 256 + h * 64 + d, f32m) * ld1(ar1, h * 64 + d, f32m);
        wr1[k * 4 + h] = s;
    } else if (which == 2) {
        for (int d = 0; d < 32; ++d) s += ld1(W2s, k * 128 + h * 32 + d, f32m) * ld1(al2, h * 32 + d, f32m);
        wl2[k * 4 + h] = s;
    } else {
        for (int d = 0; d < 32; ++d) s += ld1(W2d, k * 128 + h * 32 + d, f32m) * ld1(ar2, h * 32 + d, f32m);
        wr2[k * 4 + h] = s;
    }
}

// ---- B pre-transpose (bf16): BT1[n][k]=W1s[k][n]; BT2 = [W2s | Wres2] cols ----
__global__ void k_prepB(const void* __restrict__ W1s, const void* __restrict__ W2s,
                        const void* __restrict__ Wres2, u16* __restrict__ BT1,
                        u16* __restrict__ BT2, const int* __restrict__ mode) {
    bool f32m = (*mode) != 0;
    int id = blockIdx.x * 256 + threadIdx.x;  // 0..131071
    int which = id >> 16;
    int rem = id & 65535;
    int n = rem >> 8, k = rem & 255;  // consecutive threads: consecutive k (coalesced dst)
    if (which == 0) {
        BT1[n * 256 + k] = f2bf(ld1(W1s, (size_t)k * 256 + n, f32m));
    } else {
        float v = (n < 128) ? ld1(W2s, (size_t)k * 128 + n, f32m)
                            : ld1(Wres2, (size_t)k * 128 + (n - 128), f32m);
        BT2[n * 256 + k] = f2bf(v);
    }
}

// ---- CSR build ----
__global__ void k_deg(const int* __restrict__ dst, int* __restrict__ deg) {
    int e = blockIdx.x * 256 + threadIdx.x;
    if (e < EE) atomicAdd(&deg[dst[e]], 1);
}

__global__ void k_scan1(const int* __restrict__ deg, int* __restrict__ rowptr,
                        int* __restrict__ bsum) {
    __shared__ int sm[512];
    int t = threadIdx.x;
    int i = blockIdx.x * 512 + t;
    int v = (i < NN) ? deg[i] : 0;
    int x = v;
    sm[t] = x;
    __syncthreads();
    for (int off = 1; off < 512; off <<= 1) {
        int y = (t >= off) ? sm[t - off] : 0;
        __syncthreads();
        x += y;
        sm[t] = x;
        __syncthreads();
    }
    if (i < NN) rowptr[i] = x - v;
    if (t == 511) bsum[blockIdx.x] = x;
}

__global__ void k_scan2(const int* __restrict__ bsum, int* __restrict__ boff) {
    if (threadIdx.x == 0) {
        int run = 0;
        for (int i = 0; i < NBLK_SCAN; ++i) { boff[i] = run; run += bsum[i]; }
    }
}

__global__ void k_scan3(int* __restrict__ rowptr, const int* __restrict__ boff,
                        int* __restrict__ cursor) {
    int i = blockIdx.x * 256 + threadIdx.x;
    if (i < NN) {
        int r = rowptr[i] + boff[i >> 9];
        rowptr[i] = r;
        cursor[i] = r;
        if (i == 0) rowptr[NN] = EE;
    }
}

__global__ void k_scatter(const int* __restrict__ src, const int* __restrict__ dst,
                          int* __restrict__ cursor, int* __restrict__ csrc) {
    int e = blockIdx.x * 256 + threadIdx.x;
    if (e < EE) {
        int d = dst[e];
        int slot = atomicAdd(&cursor[d], 1);
        csrc[slot] = src[e];
    }
}

// ---- el/er (transposed out): elT[h][node] = sum_k X[node][k]*wl[k][h] ----
__global__ void k_eler(const void* __restrict__ X, int xdual,
                       const float* __restrict__ wl, const float* __restrict__ wr,
                       float* __restrict__ elT, float* __restrict__ erT,
                       const int* __restrict__ mode) {
    bool f32m = xdual && ((*mode) != 0);
    int wave = threadIdx.x >> 6, lane = threadIdx.x & 63;
    int node = blockIdx.x * 4 + wave;
    float a[4];
    load4(X, (size_t)node * 64 + lane, f32m, a);
    float accl[4] = {0, 0, 0, 0}, accr[4] = {0, 0, 0, 0};
    int k0 = lane * 4;
#pragma unroll
    for (int j = 0; j < 4; ++j) {
        float4 wlv = ((const float4*)wl)[k0 + j];
        float4 wrv = ((const float4*)wr)[k0 + j];
        accl[0] += a[j] * wlv.x; accl[1] += a[j] * wlv.y;
        accl[2] += a[j] * wlv.z; accl[3] += a[j] * wlv.w;
        accr[0] += a[j] * wrv.x; accr[1] += a[j] * wrv.y;
        accr[2] += a[j] * wrv.z; accr[3] += a[j] * wrv.w;
    }
#pragma unroll
    for (int off = 32; off > 0; off >>= 1) {
#pragma unroll
        for (int t = 0; t < 4; ++t) {
            accl[t] += __shfl_down(accl[t], off, 64);
            accr[t] += __shfl_down(accr[t], off, 64);
        }
    }
    if (lane == 0) {
#pragma unroll
        for (int t = 0; t < 4; ++t) {
            elT[t * NN + node] = accl[t];
            erT[t * NN + node] = accr[t];
        }
    }
}

// ---- MFMA GEMM: C[M][256] bf16 = A[M][256] @ B[256][256] (B given transposed) ----
// block = 256 thr (4 waves); 64x64 C tile; K staged in two 128-phases in LDS.
// LDS rows padded to 136 u16: 272 B stride -> 16B-aligned, bank stride 4 (2-way, free).
__global__ void k_gemm_mfma(const void* __restrict__ A, int aDual,
                            const u16* __restrict__ BT, u16* __restrict__ C,
                            const int* __restrict__ mode) {
    bool af32 = aDual && ((*mode) != 0);
    __shared__ u16 At[64 * 136];
    __shared__ u16 Bt[64 * 136];
    int t = threadIdx.x;
    int lane = t & 63, w = t >> 6;
    int mt = blockIdx.x >> 2, nt = blockIdx.x & 3;
    int m0 = mt * 64, n0 = nt * 64;
    f32x4 acc[4] = {};
    int q = lane >> 4, cl = lane & 15;

    for (int ph = 0; ph < 2; ++ph) {
        int kb = ph * 128;
        // stage A-tile and B-tile: 64 rows x 128 u16 each, 16B chunks
        for (int i = 0; i < 4; ++i) {
            int c = i * 256 + t;           // 0..1023
            int row = c >> 4, c16 = c & 15;
            int rowg = m0 + row;
            if (af32) {
                if (rowg < NN) {
                    const float* ap = (const float*)A + (size_t)rowg * 256 + kb + c16 * 8;
                    float4 v0 = ((const float4*)ap)[0];
                    float4 v1 = ((const float4*)ap)[1];
                    ushort4 lo = {f2bf(v0.x), f2bf(v0.y), f2bf(v0.z), f2bf(v0.w)};
                    ushort4 hi = {f2bf(v1.x), f2bf(v1.y), f2bf(v1.z), f2bf(v1.w)};
                    *(ushort4*)&At[row * 136 + c16 * 8] = lo;
                    *(ushort4*)&At[row * 136 + c16 * 8 + 4] = hi;
                } else {
                    ushort4 z = {0, 0, 0, 0};
                    *(ushort4*)&At[row * 136 + c16 * 8] = z;
                    *(ushort4*)&At[row * 136 + c16 * 8 + 4] = z;
                }
            } else {
                float4 av;
                if (rowg < NN) {
                    av = *(const float4*)((const u16*)A + (size_t)rowg * 256 + kb + c16 * 8);
                } else {
                    av = make_float4(0.f, 0.f, 0.f, 0.f);
                }
                *(float4*)&At[row * 136 + c16 * 8] = av;
            }
            float4 bv = *(const float4*)(BT + (size_t)(n0 + row) * 256 + kb + c16 * 8);
            *(float4*)&Bt[row * 136 + c16 * 8] = bv;
        }
        __syncthreads();
        int abase = (w * 16 + cl) * 136 + q * 8;
#pragma unroll
        for (int kc = 0; kc < 4; ++kc) {
            short8 af = *(const short8*)&At[abase + kc * 32];
#pragma unroll
            for (int j = 0; j < 4; ++j) {
                short8 bf = *(const short8*)&Bt[(j * 16 + cl) * 136 + q * 8 + kc * 32];
                acc[j] = __builtin_amdgcn_mfma_f32_16x16x32_bf16(af, bf, acc[j], 0, 0, 0);
            }
        }
        __syncthreads();
    }
    // store: C/D layout col=lane&15, row=quad*4+reg
#pragma unroll
    for (int j = 0; j < 4; ++j) {
#pragma unroll
        for (int r = 0; r < 4; ++r) {
            int mrow = m0 + w * 16 + q * 4 + r;
            if (mrow < NN)
                C[(size_t)mrow * 256 + n0 + j * 16 + cl] = f2bf(acc[j][r]);
        }
    }
}

// ---- layer-1 aggregation: wave/node; lane = head(lane>>4) x 4 dims (4*(lane&15)) ----
__global__ void k_agg1(const int* __restrict__ rowptr, const int* __restrict__ csrc,
                       const float* __restrict__ elT, const float* __restrict__ erT,
                       const u16* __restrict__ fs, const void* __restrict__ h_in,
                       u16* __restrict__ h1, const int* __restrict__ mode) {
    bool f32m = (*mode) != 0;
    int wave = threadIdx.x >> 6, lane = threadIdx.x & 63;
    int node = blockIdx.x * 4 + wave;
    int head = lane >> 4;
    float erh = erT[head * NN + node];
    float m = -1.0e30f, l = 0.f;
    float acc[4] = {0, 0, 0, 0};
    int beg = rowptr[node], end = rowptr[node + 1];
    for (int p = beg; p < end; ++p) {
        int s = csrc[p];
        float e = elT[head * NN + s] + erh;
        e = e > 0.f ? e : 0.2f * e;
        e = fminf(fmaxf(e, -80.f), 80.f);
        float mn = fmaxf(m, e);
        float sc = __expf(m - mn);
        float pw = __expf(e - mn);
        m = mn;
        l = l * sc + pw;
        ushort4 fv = *(const ushort4*)(fs + (size_t)s * 256 + lane * 4);
        acc[0] = acc[0] * sc + pw * bf2f(fv.x);
        acc[1] = acc[1] * sc + pw * bf2f(fv.y);
        acc[2] = acc[2] * sc + pw * bf2f(fv.z);
        acc[3] = acc[3] * sc + pw * bf2f(fv.w);
    }
    float rinv = 1.f / l;
    float res[4];
    load4(h_in, (size_t)node * 64 + lane, f32m, res);
    ushort4 o;
    float v0 = acc[0] * rinv + res[0];
    float v1 = acc[1] * rinv + res[1];
    float v2 = acc[2] * rinv + res[2];
    float v3 = acc[3] * rinv + res[3];
    o.x = f2bf(v0 > 0.f ? v0 : __expf(v0) - 1.f);
    o.y = f2bf(v1 > 0.f ? v1 : __expf(v1) - 1.f);
    o.z = f2bf(v2 > 0.f ? v2 : __expf(v2) - 1.f);
    o.w = f2bf(v3 > 0.f ? v3 : __expf(v3) - 1.f);
    ((ushort4*)h1)[(size_t)node * 64 + lane] = o;
}

// ---- layer-2 aggregation + residual + head-mean; lane = head x 2 dims ----
// c2 layout: [node][256] where cols 0..127 = fs2 (h*32+d), cols 128..255 = res2
__global__ void k_agg2(const int* __restrict__ rowptr, const int* __restrict__ csrc,
                       const float* __restrict__ elT, const float* __restrict__ erT,
                       const u16* __restrict__ c2, void* __restrict__ out,
                       const int* __restrict__ mode) {
    bool f32m = (*mode) != 0;
    int wave = threadIdx.x >> 6, lane = threadIdx.x & 63;
    int node = blockIdx.x * 4 + wave;
    int head = lane >> 4;
    float erh = erT[head * NN + node];
    float m = -1.0e30f, l = 0.f, a0 = 0.f, a1 = 0.f;
    int beg = rowptr[node], end = rowptr[node + 1];
    for (int p = beg; p < end; ++p) {
        int s = csrc[p];
        float e = elT[head * NN + s] + erh;
        e = e > 0.f ? e : 0.2f * e;
        e = fminf(fmaxf(e, -80.f), 80.f);
        float mn = fmaxf(m, e);
        float sc = __expf(m - mn);
        float pw = __expf(e - mn);
        m = mn;
        l = l * sc + pw;
        ushort2 fv = *(const ushort2*)(c2 + (size_t)s * 256 + lane * 2);
        a0 = a0 * sc + pw * bf2f(fv.x);
        a1 = a1 * sc + pw * bf2f(fv.y);
    }
    ushort2 rv = *(const ushort2*)(c2 + (size_t)node * 256 + 128 + lane * 2);
    float rinv = 1.f / l;
    float o0 = a0 * rinv + bf2f(rv.x);
    float o1 = a1 * rinv + bf2f(rv.y);
    o0 += __shfl_xor(o0, 16, 64); o0 += __shfl_xor(o0, 32, 64);
    o1 += __shfl_xor(o1, 16, 64); o1 += __shfl_xor(o1, 32, 64);
    if (lane < 16) {
        float v0 = 0.25f * o0, v1 = 0.25f * o1;
        size_t oi = (size_t)node * 32 + lane * 2;
        if (f32m) {
            ((float*)out)[oi] = v0;
            ((float*)out)[oi + 1] = v1;
        } else {
            ushort2 ov = {f2bf(v0), f2bf(v1)};
            *(ushort2*)((u16*)out + oi) = ov;
        }
    }
}

extern "C" void kernel_launch(void* const* d_in, const int* in_sizes, int n_in,
                              void* d_out, int out_size, void* d_ws, size_t ws_size,
                              hipStream_t stream) {
    int ih = 0, isrc = 1, idst = 2, iW1s = 3, iW1d = 4, ial1 = 5, iar1 = 6,
        iW2s = 7, iW2d = 8, ial2 = 9, iar2 = 10, iWres = 11;
    if (n_in >= 12 && in_sizes[0] != 12800000) {
        iW1d = 0; iW1s = 1; iW2d = 2; iW2s = 3; iWres = 4; ial1 = 5; ial2 = 6;
        iar1 = 7; iar2 = 8; idst = 9; ih = 10; isrc = 11;
    }
    const void* h     = d_in[ih];
    const int* src    = (const int*)d_in[isrc];
    const int* dst    = (const int*)d_in[idst];
    const void* W1s   = d_in[iW1s];
    const void* W1d   = d_in[iW1d];
    const void* al1   = d_in[ial1];
    const void* ar1   = d_in[iar1];
    const void* W2s   = d_in[iW2s];
    const void* W2d   = d_in[iW2d];
    const void* al2   = d_in[ial2];
    const void* ar2   = d_in[iar2];
    const void* Wres2 = d_in[iWres];

    char* w = (char*)d_ws;
    size_t off = 0;
    auto alloc = [&](size_t bytes) -> void* {
        void* p = w + off;
        off += (bytes + 255) & ~(size_t)255;
        return p;
    };
    int* mode   = (int*)alloc(256);
    float* wl1 = (float*)alloc(256 * 4 * 4);
    float* wr1 = (float*)alloc(256 * 4 * 4);
    float* wl2 = (float*)alloc(256 * 4 * 4);
    float* wr2 = (float*)alloc(256 * 4 * 4);
    int* deg    = (int*)alloc(NN * 4);
    int* cursor = (int*)alloc(NN * 4);
    int* rowptr = (int*)alloc((NN + 1) * 4);
    int* bsum   = (int*)alloc(NBLK_SCAN * 4);
    int* boff   = (int*)alloc(NBLK_SCAN * 4);
    int* csrc   = (int*)alloc((size_t)EE * 4);
    float* elT1 = (float*)alloc((size_t)NN * 4 * 4);
    float* erT1 = (float*)alloc((size_t)NN * 4 * 4);
    u16* BT1    = (u16*)alloc(256 * 256 * 2);
    u16* BT2    = (u16*)alloc(256 * 256 * 2);
    u16* fs1    = (u16*)alloc((size_t)NN * 256 * 2);   // 25.6 MB
    u16* h1     = (u16*)alloc((size_t)NN * 256 * 2);   // 25.6 MB
    // stream-ordered aliases:
    float* elT2 = elT1;
    float* erT2 = erT1;
    u16* c2     = fs1;   // fs1 dead after k_agg1; c2 = [fs2 | res2]

    hipMemsetAsync(deg, 0, NN * 4, stream);

    k_detect<<<1, 256, 0, stream>>>((const u16*)h, mode);
    k_prepB<<<512, 256, 0, stream>>>(W1s, W2s, Wres2, BT1, BT2, mode);
    k_attn_vecs<<<16, 256, 0, stream>>>(W1s, al1, W1d, ar1, W2s, al2, W2d, ar2,
                                        wl1, wr1, wl2, wr2, mode);
    k_deg<<<(EE + 255) / 256, 256, 0, stream>>>(dst, deg);
    k_scan1<<<NBLK_SCAN, 512, 0, stream>>>(deg, rowptr, bsum);
    k_scan2<<<1, 64, 0, stream>>>(bsum, boff);
    k_scan3<<<(NN + 255) / 256, 256, 0, stream>>>(rowptr, boff, cursor);
    k_scatter<<<(EE + 255) / 256, 256, 0, stream>>>(src, dst, cursor, csrc);

    // layer 1
    k_eler<<<NN / 4, 256, 0, stream>>>(h, 1, wl1, wr1, elT1, erT1, mode);
    k_gemm_mfma<<<MT * 4, 256, 0, stream>>>(h, 1, BT1, fs1, mode);
    k_agg1<<<NN / 4, 256, 0, stream>>>(rowptr, csrc, elT1, erT1, fs1, h, h1, mode);

    // layer 2 (one fused GEMM: [W2s | Wres2])
    k_eler<<<NN / 4, 256, 0, stream>>>(h1, 0, wl2, wr2, elT2, erT2, mode);
    k_gemm_mfma<<<MT * 4, 256, 0, stream>>>(h1, 0, BT2, c2, mode);
    k_agg2<<<NN / 4, 256, 0, stream>>>(rowptr, csrc, elT2, erT2, c2, d_out, mode);
}

// Round 5
// 478.528 us; speedup vs baseline: 3.2158x; 1.1120x over previous
//
#include <hip/hip_runtime.h>
#include <hip/hip_bf16.h>

#define NN 50000
#define EE 850000
#define NBLK_SCAN 98  // ceil(50000/512)
#define MT 782        // ceil(NN/64)

typedef unsigned short u16;
using short8 = __attribute__((ext_vector_type(8))) short;
using f32x4  = __attribute__((ext_vector_type(4))) float;

__device__ __forceinline__ float bf2f(u16 u) {
    union { unsigned int i; float f; } v; v.i = ((unsigned int)u) << 16; return v.f;
}
__device__ __forceinline__ u16 f2bf(float f) {
    __hip_bfloat16 h = __float2bfloat16(f);
    return *reinterpret_cast<u16*>(&h);
}

// dual-dtype input loads: f32m ? float : bf16
__device__ __forceinline__ float ld1(const void* X, size_t i, bool f32m) {
    return f32m ? ((const float*)X)[i] : bf2f(((const u16*)X)[i]);
}
__device__ __forceinline__ void load4(const void* X, size_t g, bool f32m, float o[4]) {
    if (f32m) {
        float4 v = ((const float4*)X)[g];
        o[0] = v.x; o[1] = v.y; o[2] = v.z; o[3] = v.w;
    } else {
        ushort4 v = ((const ushort4*)X)[g];
        o[0] = bf2f(v.x); o[1] = bf2f(v.y); o[2] = bf2f(v.z); o[3] = bf2f(v.w);
    }
}

// ---- dtype detector (bf16-real vs f32-reinterpreted-as-u16) ----
__global__ void k_detect(const u16* __restrict__ hh, int* __restrict__ flag) {
    __shared__ int sm[256];
    int t = threadIdx.x;
    int c = 0;
    for (int i = 0; i < 16; ++i) {
        u16 u = hh[t * 16 + i];
        int e = (u >> 7) & 0xFF;
        if (e != 0 && (e < 90 || e > 160)) ++c;
    }
    sm[t] = c;
    __syncthreads();
    for (int s = 128; s > 0; s >>= 1) {
        if (t < s) sm[t] += sm[t + s];
        __syncthreads();
    }
    if (t == 0) *flag = (sm[0] > 200) ? 1 : 0;
}

// ---- attention projection vectors: wl[k][h] = sum_d W[k][h*D+d] * a[h][d] ----
__global__ void k_attn_vecs(const void* __restrict__ W1s, const void* __restrict__ al1,
                            const void* __restrict__ W1d, const void* __restrict__ ar1,
                            const void* __restrict__ W2s, const void* __restrict__ al2,
                            const void* __restrict__ W2d, const void* __restrict__ ar2,
                            float* __restrict__ wl1, float* __restrict__ wr1,
                            float* __restrict__ wl2, float* __restrict__ wr2,
                            const int* __restrict__ mode) {
    bool f32m = (*mode) != 0;
    int id = blockIdx.x * 256 + threadIdx.x;  // 0..4095
    int which = id >> 10;
    int rem = id & 1023;
    int k = rem >> 2, h = rem & 3;
    float s = 0.f;
    if (which == 0) {
        for (int d = 0; d < 64; ++d) s += ld1(W1s, k * 256 + h * 64 + d, f32m) * ld1(al1, h * 64 + d, f32m);
        wl1[k * 4 + h] = s;
    } else if (which == 1) {
        for (int d = 0; d < 64; ++d) s += ld1(W1d, k * 256 + h * 64 + d, f32m) * ld1(ar1, h * 64 + d, f32m);
        wr1[k * 4 + h] = s;
    } else if (which == 2) {
        for (int d = 0; d < 32; ++d) s += ld1(W2s, k * 128 + h * 32 + d, f32m) * ld1(al2, h * 32 + d, f32m);
        wl2[k * 4 + h] = s;
    } else {
        for (int d = 0; d < 32; ++d) s += ld1(W2d, k * 128 + h * 32 + d, f32m) * ld1(ar2, h * 32 + d, f32m);
        wr2[k * 4 + h] = s;
    }
}

// ---- B pre-transpose (bf16): BT1[n][k]=W1s[k][n]; BT2 = [W2s | Wres2] cols ----
__global__ void k_prepB(const void* __restrict__ W1s, const void* __restrict__ W2s,
                        const void* __restrict__ Wres2, u16* __restrict__ BT1,
                        u16* __restrict__ BT2, const int* __restrict__ mode) {
    bool f32m = (*mode) != 0;
    int id = blockIdx.x * 256 + threadIdx.x;  // 0..131071
    int which = id >> 16;
    int rem = id & 65535;
    int n = rem >> 8, k = rem & 255;
    if (which == 0) {
        BT1[n * 256 + k] = f2bf(ld1(W1s, (size_t)k * 256 + n, f32m));
    } else {
        float v = (n < 128) ? ld1(W2s, (size_t)k * 128 + n, f32m)
                            : ld1(Wres2, (size_t)k * 128 + (n - 128), f32m);
        BT2[n * 256 + k] = f2bf(v);
    }
}

// ---- CSR build ----
__global__ void k_deg(const int* __restrict__ dst, int* __restrict__ deg) {
    int e = blockIdx.x * 256 + threadIdx.x;
    if (e < EE) atomicAdd(&deg[dst[e]], 1);
}

__global__ void k_scan1(const int* __restrict__ deg, int* __restrict__ rowptr,
                        int* __restrict__ bsum) {
    __shared__ int sm[512];
    int t = threadIdx.x;
    int i = blockIdx.x * 512 + t;
    int v = (i < NN) ? deg[i] : 0;
    int x = v;
    sm[t] = x;
    __syncthreads();
    for (int off = 1; off < 512; off <<= 1) {
        int y = (t >= off) ? sm[t - off] : 0;
        __syncthreads();
        x += y;
        sm[t] = x;
        __syncthreads();
    }
    if (i < NN) rowptr[i] = x - v;
    if (t == 511) bsum[blockIdx.x] = x;
}

__global__ void k_scan2(const int* __restrict__ bsum, int* __restrict__ boff) {
    if (threadIdx.x == 0) {
        int run = 0;
        for (int i = 0; i < NBLK_SCAN; ++i) { boff[i] = run; run += bsum[i]; }
    }
}

__global__ void k_scan3(int* __restrict__ rowptr, const int* __restrict__ boff,
                        int* __restrict__ cursor) {
    int i = blockIdx.x * 256 + threadIdx.x;
    if (i < NN) {
        int r = rowptr[i] + boff[i >> 9];
        rowptr[i] = r;
        cursor[i] = r;
        if (i == 0) rowptr[NN] = EE;
    }
}

__global__ void k_scatter(const int* __restrict__ src, const int* __restrict__ dst,
                          int* __restrict__ cursor, int* __restrict__ csrc) {
    int e = blockIdx.x * 256 + threadIdx.x;
    if (e < EE) {
        int d = dst[e];
        int slot = atomicAdd(&cursor[d], 1);
        csrc[slot] = src[e];
    }
}

// ---- el/er: el[node][4] = sum_k X[node][k]*wl[k][h]  (float4 per node) ----
__global__ void k_eler(const void* __restrict__ X, int xdual,
                       const float* __restrict__ wl, const float* __restrict__ wr,
                       float* __restrict__ el, float* __restrict__ er,
                       const int* __restrict__ mode) {
    bool f32m = xdual && ((*mode) != 0);
    int wave = threadIdx.x >> 6, lane = threadIdx.x & 63;
    int node = blockIdx.x * 4 + wave;
    float a[4];
    load4(X, (size_t)node * 64 + lane, f32m, a);
    float accl[4] = {0, 0, 0, 0}, accr[4] = {0, 0, 0, 0};
    int k0 = lane * 4;
#pragma unroll
    for (int j = 0; j < 4; ++j) {
        float4 wlv = ((const float4*)wl)[k0 + j];
        float4 wrv = ((const float4*)wr)[k0 + j];
        accl[0] += a[j] * wlv.x; accl[1] += a[j] * wlv.y;
        accl[2] += a[j] * wlv.z; accl[3] += a[j] * wlv.w;
        accr[0] += a[j] * wrv.x; accr[1] += a[j] * wrv.y;
        accr[2] += a[j] * wrv.z; accr[3] += a[j] * wrv.w;
    }
#pragma unroll
    for (int off = 32; off > 0; off >>= 1) {
#pragma unroll
        for (int t = 0; t < 4; ++t) {
            accl[t] += __shfl_down(accl[t], off, 64);
            accr[t] += __shfl_down(accr[t], off, 64);
        }
    }
    if (lane == 0) {
        float4 vl = {accl[0], accl[1], accl[2], accl[3]};
        float4 vr = {accr[0], accr[1], accr[2], accr[3]};
        ((float4*)el)[node] = vl;
        ((float4*)er)[node] = vr;
    }
}

// ---- MFMA GEMM: C[M][256] bf16 = A[M][256] @ B[256][256] (B given transposed) ----
__global__ void k_gemm_mfma(const void* __restrict__ A, int aDual,
                            const u16* __restrict__ BT, u16* __restrict__ C,
                            const int* __restrict__ mode) {
    bool af32 = aDual && ((*mode) != 0);
    __shared__ u16 At[64 * 136];
    __shared__ u16 Bt[64 * 136];
    int t = threadIdx.x;
    int lane = t & 63, w = t >> 6;
    int mt = blockIdx.x >> 2, nt = blockIdx.x & 3;
    int m0 = mt * 64, n0 = nt * 64;
    f32x4 acc[4] = {};
    int q = lane >> 4, cl = lane & 15;

    for (int ph = 0; ph < 2; ++ph) {
        int kb = ph * 128;
        for (int i = 0; i < 4; ++i) {
            int c = i * 256 + t;
            int row = c >> 4, c16 = c & 15;
            int rowg = m0 + row;
            if (af32) {
                if (rowg < NN) {
                    const float* ap = (const float*)A + (size_t)rowg * 256 + kb + c16 * 8;
                    float4 v0 = ((const float4*)ap)[0];
                    float4 v1 = ((const float4*)ap)[1];
                    ushort4 lo = {f2bf(v0.x), f2bf(v0.y), f2bf(v0.z), f2bf(v0.w)};
                    ushort4 hi = {f2bf(v1.x), f2bf(v1.y), f2bf(v1.z), f2bf(v1.w)};
                    *(ushort4*)&At[row * 136 + c16 * 8] = lo;
                    *(ushort4*)&At[row * 136 + c16 * 8 + 4] = hi;
                } else {
                    ushort4 z = {0, 0, 0, 0};
                    *(ushort4*)&At[row * 136 + c16 * 8] = z;
                    *(ushort4*)&At[row * 136 + c16 * 8 + 4] = z;
                }
            } else {
                float4 av;
                if (rowg < NN) {
                    av = *(const float4*)((const u16*)A + (size_t)rowg * 256 + kb + c16 * 8);
                } else {
                    av = make_float4(0.f, 0.f, 0.f, 0.f);
                }
                *(float4*)&At[row * 136 + c16 * 8] = av;
            }
            float4 bv = *(const float4*)(BT + (size_t)(n0 + row) * 256 + kb + c16 * 8);
            *(float4*)&Bt[row * 136 + c16 * 8] = bv;
        }
        __syncthreads();
        int abase = (w * 16 + cl) * 136 + q * 8;
#pragma unroll
        for (int kc = 0; kc < 4; ++kc) {
            short8 af = *(const short8*)&At[abase + kc * 32];
#pragma unroll
            for (int j = 0; j < 4; ++j) {
                short8 bf = *(const short8*)&Bt[(j * 16 + cl) * 136 + q * 8 + kc * 32];
                acc[j] = __builtin_amdgcn_mfma_f32_16x16x32_bf16(af, bf, acc[j], 0, 0, 0);
            }
        }
        __syncthreads();
    }
#pragma unroll
    for (int j = 0; j < 4; ++j) {
#pragma unroll
        for (int r = 0; r < 4; ++r) {
            int mrow = m0 + w * 16 + q * 4 + r;
            if (mrow < NN)
                C[(size_t)mrow * 256 + n0 + j * 16 + cl] = f2bf(acc[j][r]);
        }
    }
}

// ---- layer-1 aggregation, two-phase softmax (no serial rescale chain) ----
__global__ void k_agg1(const int* __restrict__ rowptr, const int* __restrict__ csrc,
                       const float* __restrict__ el, const float* __restrict__ er,
                       const u16* __restrict__ fs, const void* __restrict__ h_in,
                       u16* __restrict__ h1, const int* __restrict__ mode) {
    bool f32m = (*mode) != 0;
    int wave = threadIdx.x >> 6, lane = threadIdx.x & 63;
    int node = blockIdx.x * 4 + wave;
    int beg = rowptr[node], end = rowptr[node + 1];
    // phase 1: per-head (m,l); lane = slot(lane>>2) x head(lane&3)
    int hd = lane & 3, slot = lane >> 2;
    float erh = er[node * 4 + hd];
    float lm = -1.0e30f, ll = 0.f;
    for (int p = beg + slot; p < end; p += 16) {
        int s = csrc[p];
        float e = el[s * 4 + hd] + erh;
        e = e > 0.f ? e : 0.2f * e;
        e = fminf(fmaxf(e, -80.f), 80.f);
        float mn = fmaxf(lm, e);
        ll = ll * __expf(lm - mn) + __expf(e - mn);
        lm = mn;
    }
#pragma unroll
    for (int msk = 4; msk < 64; msk <<= 1) {
        float om = __shfl_xor(lm, msk, 64);
        float ol = __shfl_xor(ll, msk, 64);
        float mn = fmaxf(lm, om);
        ll = ll * __expf(lm - mn) + ol * __expf(om - mn);
        lm = mn;
    }
    // phase 2: weighted gather; lane = head(lane>>4) x 4 dims
    int head = lane >> 4;
    float m2 = __shfl(lm, head, 64);
    float rinv = 1.f / __shfl(ll, head, 64);
    float erh2 = __shfl(erh, head, 64);
    float a0 = 0.f, a1 = 0.f, a2 = 0.f, a3 = 0.f;
#pragma unroll 2
    for (int p = beg; p < end; ++p) {
        int s = csrc[p];
        float e = el[s * 4 + head] + erh2;
        e = e > 0.f ? e : 0.2f * e;
        e = fminf(fmaxf(e, -80.f), 80.f);
        float pw = __expf(e - m2) * rinv;
        ushort4 fv = *(const ushort4*)(fs + (size_t)s * 256 + lane * 4);
        a0 += pw * bf2f(fv.x);
        a1 += pw * bf2f(fv.y);
        a2 += pw * bf2f(fv.z);
        a3 += pw * bf2f(fv.w);
    }
    float res[4];
    load4(h_in, (size_t)node * 64 + lane, f32m, res);
    float v0 = a0 + res[0], v1 = a1 + res[1], v2 = a2 + res[2], v3 = a3 + res[3];
    ushort4 o;
    o.x = f2bf(v0 > 0.f ? v0 : __expf(v0) - 1.f);
    o.y = f2bf(v1 > 0.f ? v1 : __expf(v1) - 1.f);
    o.z = f2bf(v2 > 0.f ? v2 : __expf(v2) - 1.f);
    o.w = f2bf(v3 > 0.f ? v3 : __expf(v3) - 1.f);
    ((ushort4*)h1)[(size_t)node * 64 + lane] = o;
}

// ---- layer-2 aggregation, two-phase + residual + head-mean ----
// c2 layout: [node][256]: cols 0..127 = fs2 (h*32+d), cols 128..255 = res2
__global__ void k_agg2(const int* __restrict__ rowptr, const int* __restrict__ csrc,
                       const float* __restrict__ el, const float* __restrict__ er,
                       const u16* __restrict__ c2, void* __restrict__ out,
                       const int* __restrict__ mode) {
    bool f32m = (*mode) != 0;
    int wave = threadIdx.x >> 6, lane = threadIdx.x & 63;
    int node = blockIdx.x * 4 + wave;
    int beg = rowptr[node], end = rowptr[node + 1];
    int hd = lane & 3, slot = lane >> 2;
    float erh = er[node * 4 + hd];
    float lm = -1.0e30f, ll = 0.f;
    for (int p = beg + slot; p < end; p += 16) {
        int s = csrc[p];
        float e = el[s * 4 + hd] + erh;
        e = e > 0.f ? e : 0.2f * e;
        e = fminf(fmaxf(e, -80.f), 80.f);
        float mn = fmaxf(lm, e);
        ll = ll * __expf(lm - mn) + __expf(e - mn);
        lm = mn;
    }
#pragma unroll
    for (int msk = 4; msk < 64; msk <<= 1) {
        float om = __shfl_xor(lm, msk, 64);
        float ol = __shfl_xor(ll, msk, 64);
        float mn = fmaxf(lm, om);
        ll = ll * __expf(lm - mn) + ol * __expf(om - mn);
        lm = mn;
    }
    int head = lane >> 4;
    float m2 = __shfl(lm, head, 64);
    float rinv = 1.f / __shfl(ll, head, 64);
    float erh2 = __shfl(erh, head, 64);
    float a0 = 0.f, a1 = 0.f;
#pragma unroll 2
    for (int p = beg; p < end; ++p) {
        int s = csrc[p];
        float e = el[s * 4 + head] + erh2;
        e = e > 0.f ? e : 0.2f * e;
        e = fminf(fmaxf(e, -80.f), 80.f);
        float pw = __expf(e - m2) * rinv;
        ushort2 fv = *(const ushort2*)(c2 + (size_t)s * 256 + lane * 2);
        a0 += pw * bf2f(fv.x);
        a1 += pw * bf2f(fv.y);
    }
    ushort2 rv = *(const ushort2*)(c2 + (size_t)node * 256 + 128 + lane * 2);
    float o0 = a0 + bf2f(rv.x);
    float o1 = a1 + bf2f(rv.y);
    o0 += __shfl_xor(o0, 16, 64); o0 += __shfl_xor(o0, 32, 64);
    o1 += __shfl_xor(o1, 16, 64); o1 += __shfl_xor(o1, 32, 64);
    if (lane < 16) {
        float v0 = 0.25f * o0, v1 = 0.25f * o1;
        size_t oi = (size_t)node * 32 + lane * 2;
        if (f32m) {
            ((float*)out)[oi] = v0;
            ((float*)out)[oi + 1] = v1;
        } else {
            ushort2 ov = {f2bf(v0), f2bf(v1)};
            *(ushort2*)((u16*)out + oi) = ov;
        }
    }
}

extern "C" void kernel_launch(void* const* d_in, const int* in_sizes, int n_in,
                              void* d_out, int out_size, void* d_ws, size_t ws_size,
                              hipStream_t stream) {
    int ih = 0, isrc = 1, idst = 2, iW1s = 3, iW1d = 4, ial1 = 5, iar1 = 6,
        iW2s = 7, iW2d = 8, ial2 = 9, iar2 = 10, iWres = 11;
    if (n_in >= 12 && in_sizes[0] != 12800000) {
        iW1d = 0; iW1s = 1; iW2d = 2; iW2s = 3; iWres = 4; ial1 = 5; ial2 = 6;
        iar1 = 7; iar2 = 8; idst = 9; ih = 10; isrc = 11;
    }
    const void* h     = d_in[ih];
    const int* src    = (const int*)d_in[isrc];
    const int* dst    = (const int*)d_in[idst];
    const void* W1s   = d_in[iW1s];
    const void* W1d   = d_in[iW1d];
    const void* al1   = d_in[ial1];
    const void* ar1   = d_in[iar1];
    const void* W2s   = d_in[iW2s];
    const void* W2d   = d_in[iW2d];
    const void* al2   = d_in[ial2];
    const void* ar2   = d_in[iar2];
    const void* Wres2 = d_in[iWres];

    char* w = (char*)d_ws;
    size_t off = 0;
    auto alloc = [&](size_t bytes) -> void* {
        void* p = w + off;
        off += (bytes + 255) & ~(size_t)255;
        return p;
    };
    int* mode   = (int*)alloc(256);
    float* wl1 = (float*)alloc(256 * 4 * 4);
    float* wr1 = (float*)alloc(256 * 4 * 4);
    float* wl2 = (float*)alloc(256 * 4 * 4);
    float* wr2 = (float*)alloc(256 * 4 * 4);
    int* deg    = (int*)alloc(NN * 4);
    int* cursor = (int*)alloc(NN * 4);
    int* rowptr = (int*)alloc((NN + 1) * 4);
    int* bsum   = (int*)alloc(NBLK_SCAN * 4);
    int* boff   = (int*)alloc(NBLK_SCAN * 4);
    int* csrc   = (int*)alloc((size_t)EE * 4);
    float* el1  = (float*)alloc((size_t)NN * 4 * 4);
    float* er1  = (float*)alloc((size_t)NN * 4 * 4);
    u16* BT1    = (u16*)alloc(256 * 256 * 2);
    u16* BT2    = (u16*)alloc(256 * 256 * 2);
    u16* fs1    = (u16*)alloc((size_t)NN * 256 * 2);   // 25.6 MB
    u16* h1     = (u16*)alloc((size_t)NN * 256 * 2);   // 25.6 MB
    // stream-ordered aliases:
    float* el2 = el1;
    float* er2 = er1;
    u16* c2    = fs1;   // fs1 dead after k_agg1; c2 = [fs2 | res2]

    hipMemsetAsync(deg, 0, NN * 4, stream);

    k_detect<<<1, 256, 0, stream>>>((const u16*)h, mode);
    k_prepB<<<512, 256, 0, stream>>>(W1s, W2s, Wres2, BT1, BT2, mode);
    k_attn_vecs<<<16, 256, 0, stream>>>(W1s, al1, W1d, ar1, W2s, al2, W2d, ar2,
                                        wl1, wr1, wl2, wr2, mode);
    k_deg<<<(EE + 255) / 256, 256, 0, stream>>>(dst, deg);
    k_scan1<<<NBLK_SCAN, 512, 0, stream>>>(deg, rowptr, bsum);
    k_scan2<<<1, 64, 0, stream>>>(bsum, boff);
    k_scan3<<<(NN + 255) / 256, 256, 0, stream>>>(rowptr, boff, cursor);
    k_scatter<<<(EE + 255) / 256, 256, 0, stream>>>(src, dst, cursor, csrc);

    // layer 1
    k_eler<<<NN / 4, 256, 0, stream>>>(h, 1, wl1, wr1, el1, er1, mode);
    k_gemm_mfma<<<MT * 4, 256, 0, stream>>>(h, 1, BT1, fs1, mode);
    k_agg1<<<NN / 4, 256, 0, stream>>>(rowptr, csrc, el1, er1, fs1, h, h1, mode);

    // layer 2 (one fused GEMM: [W2s | Wres2])
    k_eler<<<NN / 4, 256, 0, stream>>>(h1, 0, wl2, wr2, el2, er2, mode);
    k_gemm_mfma<<<MT * 4, 256, 0, stream>>>(h1, 0, BT2, c2, mode);
    k_agg2<<<NN / 4, 256, 0, stream>>>(rowptr, csrc, el2, er2, c2, d_out, mode);
}

// Round 6
// 477.208 us; speedup vs baseline: 3.2247x; 1.0028x over previous
//
#include <hip/hip_runtime.h>
#include <hip/hip_bf16.h>

#define NN 50000
#define EE 850000
#define NBLK_SCAN 98  // ceil(50000/512)

typedef unsigned short u16;
using short8 = __attribute__((ext_vector_type(8))) short;
using f32x4  = __attribute__((ext_vector_type(4))) float;

__device__ __forceinline__ float bf2f(u16 u) {
    union { unsigned int i; float f; } v; v.i = ((unsigned int)u) << 16; return v.f;
}
__device__ __forceinline__ u16 f2bf(float f) {
    __hip_bfloat16 h = __float2bfloat16(f);
    return *reinterpret_cast<u16*>(&h);
}

// dual-dtype input loads: f32m ? float : bf16
__device__ __forceinline__ float ld1(const void* X, size_t i, bool f32m) {
    return f32m ? ((const float*)X)[i] : bf2f(((const u16*)X)[i]);
}
__device__ __forceinline__ void load4(const void* X, size_t g, bool f32m, float o[4]) {
    if (f32m) {
        float4 v = ((const float4*)X)[g];
        o[0] = v.x; o[1] = v.y; o[2] = v.z; o[3] = v.w;
    } else {
        ushort4 v = ((const ushort4*)X)[g];
        o[0] = bf2f(v.x); o[1] = bf2f(v.y); o[2] = bf2f(v.z); o[3] = bf2f(v.w);
    }
}

// ---- dtype detector (bf16-real vs f32-reinterpreted-as-u16) ----
__global__ void k_detect(const u16* __restrict__ hh, int* __restrict__ flag) {
    __shared__ int sm[256];
    int t = threadIdx.x;
    int c = 0;
    for (int i = 0; i < 16; ++i) {
        u16 u = hh[t * 16 + i];
        int e = (u >> 7) & 0xFF;
        if (e != 0 && (e < 90 || e > 160)) ++c;
    }
    sm[t] = c;
    __syncthreads();
    for (int s = 128; s > 0; s >>= 1) {
        if (t < s) sm[t] += sm[t + s];
        __syncthreads();
    }
    if (t == 0) *flag = (sm[0] > 200) ? 1 : 0;
}

// ---- attention projection vectors: wl[k][h] = sum_d W[k][h*D+d] * a[h][d] ----
__global__ void k_attn_vecs(const void* __restrict__ W1s, const void* __restrict__ al1,
                            const void* __restrict__ W1d, const void* __restrict__ ar1,
                            const void* __restrict__ W2s, const void* __restrict__ al2,
                            const void* __restrict__ W2d, const void* __restrict__ ar2,
                            float* __restrict__ wl1, float* __restrict__ wr1,
                            float* __restrict__ wl2, float* __restrict__ wr2,
                            const int* __restrict__ mode) {
    bool f32m = (*mode) != 0;
    int id = blockIdx.x * 256 + threadIdx.x;  // 0..4095
    int which = id >> 10;
    int rem = id & 1023;
    int k = rem >> 2, h = rem & 3;
    float s = 0.f;
    if (which == 0) {
        for (int d = 0; d < 64; ++d) s += ld1(W1s, k * 256 + h * 64 + d, f32m) * ld1(al1, h * 64 + d, f32m);
        wl1[k * 4 + h] = s;
    } else if (which == 1) {
        for (int d = 0; d < 64; ++d) s += ld1(W1d, k * 256 + h * 64 + d, f32m) * ld1(ar1, h * 64 + d, f32m);
        wr1[k * 4 + h] = s;
    } else if (which == 2) {
        for (int d = 0; d < 32; ++d) s += ld1(W2s, k * 128 + h * 32 + d, f32m) * ld1(al2, h * 32 + d, f32m);
        wl2[k * 4 + h] = s;
    } else {
        for (int d = 0; d < 32; ++d) s += ld1(W2d, k * 128 + h * 32 + d, f32m) * ld1(ar2, h * 32 + d, f32m);
        wr2[k * 4 + h] = s;
    }
}

// ---- B pre-transpose (bf16): BT1[n][k]=W1s[k][n]; BT2 = [W2s | Wres2] cols ----
__global__ void k_prepB(const void* __restrict__ W1s, const void* __restrict__ W2s,
                        const void* __restrict__ Wres2, u16* __restrict__ BT1,
                        u16* __restrict__ BT2, const int* __restrict__ mode) {
    bool f32m = (*mode) != 0;
    int id = blockIdx.x * 256 + threadIdx.x;  // 0..131071
    int which = id >> 16;
    int rem = id & 65535;
    int n = rem >> 8, k = rem & 255;
    if (which == 0) {
        BT1[n * 256 + k] = f2bf(ld1(W1s, (size_t)k * 256 + n, f32m));
    } else {
        float v = (n < 128) ? ld1(W2s, (size_t)k * 128 + n, f32m)
                            : ld1(Wres2, (size_t)k * 128 + (n - 128), f32m);
        BT2[n * 256 + k] = f2bf(v);
    }
}

// ---- CSR build ----
__global__ void k_deg(const int* __restrict__ dst, int* __restrict__ deg) {
    int e = blockIdx.x * 256 + threadIdx.x;
    if (e < EE) atomicAdd(&deg[dst[e]], 1);
}

__global__ void k_scan1(const int* __restrict__ deg, int* __restrict__ rowptr,
                        int* __restrict__ bsum) {
    __shared__ int sm[512];
    int t = threadIdx.x;
    int i = blockIdx.x * 512 + t;
    int v = (i < NN) ? deg[i] : 0;
    int x = v;
    sm[t] = x;
    __syncthreads();
    for (int off = 1; off < 512; off <<= 1) {
        int y = (t >= off) ? sm[t - off] : 0;
        __syncthreads();
        x += y;
        sm[t] = x;
        __syncthreads();
    }
    if (i < NN) rowptr[i] = x - v;
    if (t == 511) bsum[blockIdx.x] = x;
}

__global__ void k_scan2(const int* __restrict__ bsum, int* __restrict__ boff) {
    if (threadIdx.x == 0) {
        int run = 0;
        for (int i = 0; i < NBLK_SCAN; ++i) { boff[i] = run; run += bsum[i]; }
    }
}

__global__ void k_scan3(int* __restrict__ rowptr, const int* __restrict__ boff,
                        int* __restrict__ cursor) {
    int i = blockIdx.x * 256 + threadIdx.x;
    if (i < NN) {
        int r = rowptr[i] + boff[i >> 9];
        rowptr[i] = r;
        cursor[i] = r;
        if (i == 0) rowptr[NN] = EE;
    }
}

__global__ void k_scatter(const int* __restrict__ src, const int* __restrict__ dst,
                          int* __restrict__ cursor, int* __restrict__ csrc,
                          int* __restrict__ cdst) {
    int e = blockIdx.x * 256 + threadIdx.x;
    if (e < EE) {
        int d = dst[e];
        int slot = atomicAdd(&cursor[d], 1);
        csrc[slot] = src[e];
        cdst[slot] = d;
    }
}

// ---- el/er: el[node][4] = sum_k X[node][k]*wl[k][h]  (float4 per node) ----
__global__ void k_eler(const void* __restrict__ X, int xdual,
                       const float* __restrict__ wl, const float* __restrict__ wr,
                       float* __restrict__ el, float* __restrict__ er,
                       const int* __restrict__ mode) {
    bool f32m = xdual && ((*mode) != 0);
    int wave = threadIdx.x >> 6, lane = threadIdx.x & 63;
    int node = blockIdx.x * 4 + wave;
    float a[4];
    load4(X, (size_t)node * 64 + lane, f32m, a);
    float accl[4] = {0, 0, 0, 0}, accr[4] = {0, 0, 0, 0};
    int k0 = lane * 4;
#pragma unroll
    for (int j = 0; j < 4; ++j) {
        float4 wlv = ((const float4*)wl)[k0 + j];
        float4 wrv = ((const float4*)wr)[k0 + j];
        accl[0] += a[j] * wlv.x; accl[1] += a[j] * wlv.y;
        accl[2] += a[j] * wlv.z; accl[3] += a[j] * wlv.w;
        accr[0] += a[j] * wrv.x; accr[1] += a[j] * wrv.y;
        accr[2] += a[j] * wrv.z; accr[3] += a[j] * wrv.w;
    }
#pragma unroll
    for (int off = 32; off > 0; off >>= 1) {
#pragma unroll
        for (int t = 0; t < 4; ++t) {
            accl[t] += __shfl_down(accl[t], off, 64);
            accr[t] += __shfl_down(accr[t], off, 64);
        }
    }
    if (lane == 0) {
        float4 vl = {accl[0], accl[1], accl[2], accl[3]};
        float4 vr = {accr[0], accr[1], accr[2], accr[3]};
        ((float4*)el)[node] = vl;
        ((float4*)er)[node] = vr;
    }
}

// ---- per-node softmax stats: mlm[node][4]=max, mlr[node][4]=1/sum ----
__global__ void k_ml(const int* __restrict__ rowptr, const int* __restrict__ csrc,
                     const float* __restrict__ el, const float* __restrict__ er,
                     float* __restrict__ mlm, float* __restrict__ mlr) {
    int wave = threadIdx.x >> 6, lane = threadIdx.x & 63;
    int node = blockIdx.x * 4 + wave;
    int beg = rowptr[node], end = rowptr[node + 1];
    int hd = lane & 3, slot = lane >> 2;
    float erh = er[node * 4 + hd];
    float lm = -1.0e30f, ll = 0.f;
    for (int p = beg + slot; p < end; p += 16) {
        int s = csrc[p];
        float e = el[s * 4 + hd] + erh;
        e = e > 0.f ? e : 0.2f * e;
        e = fminf(fmaxf(e, -80.f), 80.f);
        float mn = fmaxf(lm, e);
        ll = ll * __expf(lm - mn) + __expf(e - mn);
        lm = mn;
    }
#pragma unroll
    for (int msk = 4; msk < 64; msk <<= 1) {
        float om = __shfl_xor(lm, msk, 64);
        float ol = __shfl_xor(ll, msk, 64);
        float mn = fmaxf(lm, om);
        ll = ll * __expf(lm - mn) + ol * __expf(om - mn);
        lm = mn;
    }
    if (lane < 4) {
        mlm[node * 4 + lane] = lm;
        mlr[node * 4 + lane] = 1.f / ll;
    }
}

// ---- edge attention weights: aw[p][h] = exp(e - m[d]) / l[d]  (bf16) ----
__global__ void k_aw(const int* __restrict__ csrc, const int* __restrict__ cdst,
                     const float* __restrict__ el, const float* __restrict__ er,
                     const float* __restrict__ mlm, const float* __restrict__ mlr,
                     u16* __restrict__ aw) {
    int p = blockIdx.x * 256 + threadIdx.x;
    if (p >= EE) return;
    int s = csrc[p], d = cdst[p];
    float4 eL = ((const float4*)el)[s];
    float4 eR = ((const float4*)er)[d];
    float4 m4 = ((const float4*)mlm)[d];
    float4 r4 = ((const float4*)mlr)[d];
    float ev[4] = {eL.x + eR.x, eL.y + eR.y, eL.z + eR.z, eL.w + eR.w};
    float mm[4] = {m4.x, m4.y, m4.z, m4.w};
    float rr[4] = {r4.x, r4.y, r4.z, r4.w};
    ushort4 o;
    u16* op = (u16*)&o;
#pragma unroll
    for (int t = 0; t < 4; ++t) {
        float e = ev[t];
        e = e > 0.f ? e : 0.2f * e;
        e = fminf(fmaxf(e, -80.f), 80.f);
        op[t] = f2bf(__expf(e - mm[t]) * rr[t]);
    }
    ((ushort4*)aw)[p] = o;
}

// ---- MFMA GEMM: C[M][256] bf16 = A[M][256] @ B (BT transposed [256n][256k]) ----
// 128x128 C-tile per block (4 waves, 2x2); BK=64, 4 phases. LDS pad 72 u16/row.
__global__ void k_gemm_mfma(const void* __restrict__ A, int aDual,
                            const u16* __restrict__ BT, u16* __restrict__ C,
                            const int* __restrict__ mode) {
    bool af32 = aDual && ((*mode) != 0);
    __shared__ u16 At[128 * 72];
    __shared__ u16 Bt[128 * 72];
    int t = threadIdx.x;
    int lane = t & 63, w = t >> 6;
    int mt = blockIdx.x >> 1, nt = blockIdx.x & 1;
    int m0 = mt * 128, n0 = nt * 128;
    int wr = (w >> 1) * 64, wc = (w & 1) * 64;
    f32x4 acc[4][4] = {};
    int q = lane >> 4, cl = lane & 15;

    for (int ph = 0; ph < 4; ++ph) {
        int kb = ph * 64;
        // stage A/B tiles: 128 rows x 64 u16 each, in 8-u16 (16B) chunks
        for (int it = 0; it < 4; ++it) {
            int c = it * 256 + t;        // 0..1023
            int row = c >> 3, c8 = c & 7;
            int rowg = m0 + row;
            if (af32) {
                if (rowg < NN) {
                    const float* ap = (const float*)A + (size_t)rowg * 256 + kb + c8 * 8;
                    float4 v0 = ((const float4*)ap)[0];
                    float4 v1 = ((const float4*)ap)[1];
                    ushort4 lo = {f2bf(v0.x), f2bf(v0.y), f2bf(v0.z), f2bf(v0.w)};
                    ushort4 hi = {f2bf(v1.x), f2bf(v1.y), f2bf(v1.z), f2bf(v1.w)};
                    *(ushort4*)&At[row * 72 + c8 * 8] = lo;
                    *(ushort4*)&At[row * 72 + c8 * 8 + 4] = hi;
                } else {
                    ushort4 z = {0, 0, 0, 0};
                    *(ushort4*)&At[row * 72 + c8 * 8] = z;
                    *(ushort4*)&At[row * 72 + c8 * 8 + 4] = z;
                }
            } else {
                float4 av;
                if (rowg < NN) {
                    av = *(const float4*)((const u16*)A + (size_t)rowg * 256 + kb + c8 * 8);
                } else {
                    av = make_float4(0.f, 0.f, 0.f, 0.f);
                }
                *(float4*)&At[row * 72 + c8 * 8] = av;
            }
            float4 bv = *(const float4*)(BT + (size_t)(n0 + row) * 256 + kb + c8 * 8);
            *(float4*)&Bt[row * 72 + c8 * 8] = bv;
        }
        __syncthreads();
#pragma unroll
        for (int ks = 0; ks < 2; ++ks) {
            short8 af[4], bf[4];
#pragma unroll
            for (int i = 0; i < 4; ++i)
                af[i] = *(const short8*)&At[(wr + i * 16 + cl) * 72 + ks * 32 + q * 8];
#pragma unroll
            for (int j = 0; j < 4; ++j)
                bf[j] = *(const short8*)&Bt[(wc + j * 16 + cl) * 72 + ks * 32 + q * 8];
#pragma unroll
            for (int i = 0; i < 4; ++i)
#pragma unroll
                for (int j = 0; j < 4; ++j)
                    acc[i][j] = __builtin_amdgcn_mfma_f32_16x16x32_bf16(af[i], bf[j], acc[i][j], 0, 0, 0);
        }
        __syncthreads();
    }
#pragma unroll
    for (int i = 0; i < 4; ++i)
#pragma unroll
        for (int j = 0; j < 4; ++j)
#pragma unroll
            for (int r = 0; r < 4; ++r) {
                int mrow = m0 + wr + i * 16 + q * 4 + r;
                if (mrow < NN)
                    C[(size_t)mrow * 256 + n0 + wc + j * 16 + cl] = f2bf(acc[i][j][r]);
            }
}

// ---- layer-1 aggregation: pure weighted gather (aw precomputed) ----
__global__ void k_agg1(const int* __restrict__ rowptr, const int* __restrict__ csrc,
                       const u16* __restrict__ aw, const u16* __restrict__ fs,
                       const void* __restrict__ h_in, u16* __restrict__ h1,
                       const int* __restrict__ mode) {
    bool f32m = (*mode) != 0;
    int wave = threadIdx.x >> 6, lane = threadIdx.x & 63;
    int node = blockIdx.x * 4 + wave;
    int beg = rowptr[node], end = rowptr[node + 1];
    int head = lane >> 4;
    float a0 = 0.f, a1 = 0.f, a2 = 0.f, a3 = 0.f;
#pragma unroll 2
    for (int p = beg; p < end; ++p) {
        int s = csrc[p];
        float pw = bf2f(aw[(size_t)p * 4 + head]);
        ushort4 fv = *(const ushort4*)(fs + (size_t)s * 256 + lane * 4);
        a0 += pw * bf2f(fv.x);
        a1 += pw * bf2f(fv.y);
        a2 += pw * bf2f(fv.z);
        a3 += pw * bf2f(fv.w);
    }
    float res[4];
    load4(h_in, (size_t)node * 64 + lane, f32m, res);
    float v0 = a0 + res[0], v1 = a1 + res[1], v2 = a2 + res[2], v3 = a3 + res[3];
    ushort4 o;
    o.x = f2bf(v0 > 0.f ? v0 : __expf(v0) - 1.f);
    o.y = f2bf(v1 > 0.f ? v1 : __expf(v1) - 1.f);
    o.z = f2bf(v2 > 0.f ? v2 : __expf(v2) - 1.f);
    o.w = f2bf(v3 > 0.f ? v3 : __expf(v3) - 1.f);
    ((ushort4*)h1)[(size_t)node * 64 + lane] = o;
}

// ---- layer-2 aggregation + residual + head-mean (aw precomputed) ----
// c2 layout: [node][256]: cols 0..127 = fs2 (h*32+d), cols 128..255 = res2
__global__ void k_agg2(const int* __restrict__ rowptr, const int* __restrict__ csrc,
                       const u16* __restrict__ aw, const u16* __restrict__ c2,
                       void* __restrict__ out, const int* __restrict__ mode) {
    bool f32m = (*mode) != 0;
    int wave = threadIdx.x >> 6, lane = threadIdx.x & 63;
    int node = blockIdx.x * 4 + wave;
    int beg = rowptr[node], end = rowptr[node + 1];
    int head = lane >> 4;
    float a0 = 0.f, a1 = 0.f;
#pragma unroll 2
    for (int p = beg; p < end; ++p) {
        int s = csrc[p];
        float pw = bf2f(aw[(size_t)p * 4 + head]);
        ushort2 fv = *(const ushort2*)(c2 + (size_t)s * 256 + lane * 2);
        a0 += pw * bf2f(fv.x);
        a1 += pw * bf2f(fv.y);
    }
    ushort2 rv = *(const ushort2*)(c2 + (size_t)node * 256 + 128 + lane * 2);
    float o0 = a0 + bf2f(rv.x);
    float o1 = a1 + bf2f(rv.y);
    o0 += __shfl_xor(o0, 16, 64); o0 += __shfl_xor(o0, 32, 64);
    o1 += __shfl_xor(o1, 16, 64); o1 += __shfl_xor(o1, 32, 64);
    if (lane < 16) {
        float v0 = 0.25f * o0, v1 = 0.25f * o1;
        size_t oi = (size_t)node * 32 + lane * 2;
        if (f32m) {
            ((float*)out)[oi] = v0;
            ((float*)out)[oi + 1] = v1;
        } else {
            ushort2 ov = {f2bf(v0), f2bf(v1)};
            *(ushort2*)((u16*)out + oi) = ov;
        }
    }
}

extern "C" void kernel_launch(void* const* d_in, const int* in_sizes, int n_in,
                              void* d_out, int out_size, void* d_ws, size_t ws_size,
                              hipStream_t stream) {
    int ih = 0, isrc = 1, idst = 2, iW1s = 3, iW1d = 4, ial1 = 5, iar1 = 6,
        iW2s = 7, iW2d = 8, ial2 = 9, iar2 = 10, iWres = 11;
    if (n_in >= 12 && in_sizes[0] != 12800000) {
        iW1d = 0; iW1s = 1; iW2d = 2; iW2s = 3; iWres = 4; ial1 = 5; ial2 = 6;
        iar1 = 7; iar2 = 8; idst = 9; ih = 10; isrc = 11;
    }
    const void* h     = d_in[ih];
    const int* src    = (const int*)d_in[isrc];
    const int* dst    = (const int*)d_in[idst];
    const void* W1s   = d_in[iW1s];
    const void* W1d   = d_in[iW1d];
    const void* al1   = d_in[ial1];
    const void* ar1   = d_in[iar1];
    const void* W2s   = d_in[iW2s];
    const void* W2d   = d_in[iW2d];
    const void* al2   = d_in[ial2];
    const void* ar2   = d_in[iar2];
    const void* Wres2 = d_in[iWres];

    char* w = (char*)d_ws;
    size_t off = 0;
    auto alloc = [&](size_t bytes) -> void* {
        void* p = w + off;
        off += (bytes + 255) & ~(size_t)255;
        return p;
    };
    int* mode   = (int*)alloc(256);
    float* wl1 = (float*)alloc(256 * 4 * 4);
    float* wr1 = (float*)alloc(256 * 4 * 4);
    float* wl2 = (float*)alloc(256 * 4 * 4);
    float* wr2 = (float*)alloc(256 * 4 * 4);
    int* deg    = (int*)alloc(NN * 4);
    int* cursor = (int*)alloc(NN * 4);
    int* rowptr = (int*)alloc((NN + 1) * 4);
    int* bsum   = (int*)alloc(NBLK_SCAN * 4);
    int* boff   = (int*)alloc(NBLK_SCAN * 4);
    int* csrc   = (int*)alloc((size_t)EE * 4);
    int* cdst   = (int*)alloc((size_t)EE * 4);
    float* el1  = (float*)alloc((size_t)NN * 4 * 4);
    float* er1  = (float*)alloc((size_t)NN * 4 * 4);
    float* mlm  = (float*)alloc((size_t)NN * 4 * 4);
    float* mlr  = (float*)alloc((size_t)NN * 4 * 4);
    u16* aw     = (u16*)alloc((size_t)EE * 4 * 2);     // 6.8 MB
    u16* BT1    = (u16*)alloc(256 * 256 * 2);
    u16* BT2    = (u16*)alloc(256 * 256 * 2);
    u16* fs1    = (u16*)alloc((size_t)NN * 256 * 2);   // 25.6 MB
    u16* h1     = (u16*)alloc((size_t)NN * 256 * 2);   // 25.6 MB
    // stream-ordered aliases:
    float* el2 = el1;
    float* er2 = er1;
    u16* c2    = fs1;   // fs1 dead after k_agg1; c2 = [fs2 | res2]

    hipMemsetAsync(deg, 0, NN * 4, stream);

    k_detect<<<1, 256, 0, stream>>>((const u16*)h, mode);
    k_prepB<<<512, 256, 0, stream>>>(W1s, W2s, Wres2, BT1, BT2, mode);
    k_attn_vecs<<<16, 256, 0, stream>>>(W1s, al1, W1d, ar1, W2s, al2, W2d, ar2,
                                        wl1, wr1, wl2, wr2, mode);
    k_deg<<<(EE + 255) / 256, 256, 0, stream>>>(dst, deg);
    k_scan1<<<NBLK_SCAN, 512, 0, stream>>>(deg, rowptr, bsum);
    k_scan2<<<1, 64, 0, stream>>>(bsum, boff);
    k_scan3<<<(NN + 255) / 256, 256, 0, stream>>>(rowptr, boff, cursor);
    k_scatter<<<(EE + 255) / 256, 256, 0, stream>>>(src, dst, cursor, csrc, cdst);

    // layer 1
    k_eler<<<NN / 4, 256, 0, stream>>>(h, 1, wl1, wr1, el1, er1, mode);
    k_ml<<<NN / 4, 256, 0, stream>>>(rowptr, csrc, el1, er1, mlm, mlr);
    k_aw<<<(EE + 255) / 256, 256, 0, stream>>>(csrc, cdst, el1, er1, mlm, mlr, aw);
    k_gemm_mfma<<<391 * 2, 256, 0, stream>>>(h, 1, BT1, fs1, mode);
    k_agg1<<<NN / 4, 256, 0, stream>>>(rowptr, csrc, aw, fs1, h, h1, mode);

    // layer 2 (one fused GEMM: [W2s | Wres2]); aw/ml/el reused stream-ordered
    k_eler<<<NN / 4, 256, 0, stream>>>(h1, 0, wl2, wr2, el2, er2, mode);
    k_ml<<<NN / 4, 256, 0, stream>>>(rowptr, csrc, el2, er2, mlm, mlr);
    k_aw<<<(EE + 255) / 256, 256, 0, stream>>>(csrc, cdst, el2, er2, mlm, mlr, aw);
    k_gemm_mfma<<<391 * 2, 256, 0, stream>>>(h1, 0, BT2, c2, mode);
    k_agg2<<<NN / 4, 256, 0, stream>>>(rowptr, csrc, aw, c2, d_out, mode);
}

// Round 7
// 437.364 us; speedup vs baseline: 3.5184x; 1.0911x over previous
//
#include <hip/hip_runtime.h>
#include <hip/hip_bf16.h>

#define NN 50000
#define EE 850000
#define NBLK_SCAN 98  // ceil(50000/512)

typedef unsigned short u16;
using short8 = __attribute__((ext_vector_type(8))) short;
using f32x4  = __attribute__((ext_vector_type(4))) float;

__device__ __forceinline__ float bf2f(u16 u) {
    union { unsigned int i; float f; } v; v.i = ((unsigned int)u) << 16; return v.f;
}
__device__ __forceinline__ u16 f2bf(float f) {
    __hip_bfloat16 h = __float2bfloat16(f);
    return *reinterpret_cast<u16*>(&h);
}

// dual-dtype input loads: f32m ? float : bf16
__device__ __forceinline__ float ld1(const void* X, size_t i, bool f32m) {
    return f32m ? ((const float*)X)[i] : bf2f(((const u16*)X)[i]);
}
__device__ __forceinline__ void load4(const void* X, size_t g, bool f32m, float o[4]) {
    if (f32m) {
        float4 v = ((const float4*)X)[g];
        o[0] = v.x; o[1] = v.y; o[2] = v.z; o[3] = v.w;
    } else {
        ushort4 v = ((const ushort4*)X)[g];
        o[0] = bf2f(v.x); o[1] = bf2f(v.y); o[2] = bf2f(v.z); o[3] = bf2f(v.w);
    }
}

// ---- dtype detector (bf16-real vs f32-reinterpreted-as-u16) ----
__global__ void k_detect(const u16* __restrict__ hh, int* __restrict__ flag) {
    __shared__ int sm[256];
    int t = threadIdx.x;
    int c = 0;
    for (int i = 0; i < 16; ++i) {
        u16 u = hh[t * 16 + i];
        int e = (u >> 7) & 0xFF;
        if (e != 0 && (e < 90 || e > 160)) ++c;
    }
    sm[t] = c;
    __syncthreads();
    for (int s = 128; s > 0; s >>= 1) {
        if (t < s) sm[t] += sm[t + s];
        __syncthreads();
    }
    if (t == 0) *flag = (sm[0] > 200) ? 1 : 0;
}

// ---- fused prep: blocks 0..511 = B-transpose, 512..527 = attn vecs, rest = deg ----
__global__ void k_prep(const void* __restrict__ W1s, const void* __restrict__ al1,
                       const void* __restrict__ W1d, const void* __restrict__ ar1,
                       const void* __restrict__ W2s, const void* __restrict__ al2,
                       const void* __restrict__ W2d, const void* __restrict__ ar2,
                       const void* __restrict__ Wres2, const int* __restrict__ dst,
                       u16* __restrict__ BT1, u16* __restrict__ BT2,
                       float* __restrict__ wl1, float* __restrict__ wr1,
                       float* __restrict__ wl2, float* __restrict__ wr2,
                       int* __restrict__ deg, const int* __restrict__ mode) {
    int bid = blockIdx.x;
    if (bid >= 528) {
        int e = (bid - 528) * 256 + threadIdx.x;
        if (e < EE) atomicAdd(&deg[dst[e]], 1);
        return;
    }
    bool f32m = (*mode) != 0;
    if (bid < 512) {
        // B pre-transpose: BT1[n][k] = W1s[k][n]; BT2 = [W2s | Wres2] columns
        int id = bid * 256 + threadIdx.x;  // 0..131071
        int which = id >> 16;
        int rem = id & 65535;
        int n = rem >> 8, k = rem & 255;
        if (which == 0) {
            BT1[n * 256 + k] = f2bf(ld1(W1s, (size_t)k * 256 + n, f32m));
        } else {
            float v = (n < 128) ? ld1(W2s, (size_t)k * 128 + n, f32m)
                                : ld1(Wres2, (size_t)k * 128 + (n - 128), f32m);
            BT2[n * 256 + k] = f2bf(v);
        }
    } else {
        // attention projection vectors: wl[k][h] = sum_d W[k][h*D+d]*a[h][d]
        int id = (bid - 512) * 256 + threadIdx.x;  // 0..4095
        int which = id >> 10;
        int rem = id & 1023;
        int k = rem >> 2, h = rem & 3;
        float s = 0.f;
        if (which == 0) {
            for (int d = 0; d < 64; ++d) s += ld1(W1s, k * 256 + h * 64 + d, f32m) * ld1(al1, h * 64 + d, f32m);
            wl1[k * 4 + h] = s;
        } else if (which == 1) {
            for (int d = 0; d < 64; ++d) s += ld1(W1d, k * 256 + h * 64 + d, f32m) * ld1(ar1, h * 64 + d, f32m);
            wr1[k * 4 + h] = s;
        } else if (which == 2) {
            for (int d = 0; d < 32; ++d) s += ld1(W2s, k * 128 + h * 32 + d, f32m) * ld1(al2, h * 32 + d, f32m);
            wl2[k * 4 + h] = s;
        } else {
            for (int d = 0; d < 32; ++d) s += ld1(W2d, k * 128 + h * 32 + d, f32m) * ld1(ar2, h * 32 + d, f32m);
            wr2[k * 4 + h] = s;
        }
    }
}

// ---- CSR scan ----
__global__ void k_scan1(const int* __restrict__ deg, int* __restrict__ rowptr,
                        int* __restrict__ bsum) {
    __shared__ int sm[512];
    int t = threadIdx.x;
    int i = blockIdx.x * 512 + t;
    int v = (i < NN) ? deg[i] : 0;
    int x = v;
    sm[t] = x;
    __syncthreads();
    for (int off = 1; off < 512; off <<= 1) {
        int y = (t >= off) ? sm[t - off] : 0;
        __syncthreads();
        x += y;
        sm[t] = x;
        __syncthreads();
    }
    if (i < NN) rowptr[i] = x - v;
    if (t == 511) bsum[blockIdx.x] = x;
}

__global__ void k_scan2(const int* __restrict__ bsum, int* __restrict__ boff) {
    __shared__ int sm[128];
    int t = threadIdx.x;
    int v = (t < NBLK_SCAN) ? bsum[t] : 0;
    int x = v;
    sm[t] = x;
    __syncthreads();
    for (int off = 1; off < 128; off <<= 1) {
        int y = (t >= off) ? sm[t - off] : 0;
        __syncthreads();
        x += y;
        sm[t] = x;
        __syncthreads();
    }
    if (t < NBLK_SCAN) boff[t] = x - v;
}

__global__ void k_scan3(int* __restrict__ rowptr, const int* __restrict__ boff,
                        int* __restrict__ cursor) {
    int i = blockIdx.x * 256 + threadIdx.x;
    if (i < NN) {
        int r = rowptr[i] + boff[i >> 9];
        rowptr[i] = r;
        cursor[i] = r;
        if (i == 0) rowptr[NN] = EE;
    }
}

__global__ void k_scatter(const int* __restrict__ src, const int* __restrict__ dst,
                          int* __restrict__ cursor, int* __restrict__ csrc) {
    int e = blockIdx.x * 256 + threadIdx.x;
    if (e < EE) {
        int d = dst[e];
        int slot = atomicAdd(&cursor[d], 1);
        csrc[slot] = src[e];
    }
}

// ---- el/er: el[node][4] = sum_k X[node][k]*wl[k][h]  (float4 per node) ----
__global__ void k_eler(const void* __restrict__ X, int xdual,
                       const float* __restrict__ wl, const float* __restrict__ wr,
                       float* __restrict__ el, float* __restrict__ er,
                       const int* __restrict__ mode) {
    bool f32m = xdual && ((*mode) != 0);
    int wave = threadIdx.x >> 6, lane = threadIdx.x & 63;
    int node = blockIdx.x * 4 + wave;
    float a[4];
    load4(X, (size_t)node * 64 + lane, f32m, a);
    float accl[4] = {0, 0, 0, 0}, accr[4] = {0, 0, 0, 0};
    int k0 = lane * 4;
#pragma unroll
    for (int j = 0; j < 4; ++j) {
        float4 wlv = ((const float4*)wl)[k0 + j];
        float4 wrv = ((const float4*)wr)[k0 + j];
        accl[0] += a[j] * wlv.x; accl[1] += a[j] * wlv.y;
        accl[2] += a[j] * wlv.z; accl[3] += a[j] * wlv.w;
        accr[0] += a[j] * wrv.x; accr[1] += a[j] * wrv.y;
        accr[2] += a[j] * wrv.z; accr[3] += a[j] * wrv.w;
    }
#pragma unroll
    for (int off = 32; off > 0; off >>= 1) {
#pragma unroll
        for (int t = 0; t < 4; ++t) {
            accl[t] += __shfl_down(accl[t], off, 64);
            accr[t] += __shfl_down(accr[t], off, 64);
        }
    }
    if (lane == 0) {
        float4 vl = {accl[0], accl[1], accl[2], accl[3]};
        float4 vr = {accr[0], accr[1], accr[2], accr[3]};
        ((float4*)el)[node] = vl;
        ((float4*)er)[node] = vr;
    }
}

// ---- MFMA GEMM: C[M][256] bf16 = A[M][256] @ B (BT transposed [256n][256k]) ----
// 128x128 C-tile per block (4 waves, 2x2); BK=64, 4 phases. LDS pad 72 u16/row.
__global__ void k_gemm_mfma(const void* __restrict__ A, int aDual,
                            const u16* __restrict__ BT, u16* __restrict__ C,
                            const int* __restrict__ mode) {
    bool af32 = aDual && ((*mode) != 0);
    __shared__ u16 At[128 * 72];
    __shared__ u16 Bt[128 * 72];
    int t = threadIdx.x;
    int lane = t & 63, w = t >> 6;
    int mt = blockIdx.x >> 1, nt = blockIdx.x & 1;
    int m0 = mt * 128, n0 = nt * 128;
    int wr = (w >> 1) * 64, wc = (w & 1) * 64;
    f32x4 acc[4][4] = {};
    int q = lane >> 4, cl = lane & 15;

    for (int ph = 0; ph < 4; ++ph) {
        int kb = ph * 64;
        for (int it = 0; it < 4; ++it) {
            int c = it * 256 + t;        // 0..1023
            int row = c >> 3, c8 = c & 7;
            int rowg = m0 + row;
            if (af32) {
                if (rowg < NN) {
                    const float* ap = (const float*)A + (size_t)rowg * 256 + kb + c8 * 8;
                    float4 v0 = ((const float4*)ap)[0];
                    float4 v1 = ((const float4*)ap)[1];
                    ushort4 lo = {f2bf(v0.x), f2bf(v0.y), f2bf(v0.z), f2bf(v0.w)};
                    ushort4 hi = {f2bf(v1.x), f2bf(v1.y), f2bf(v1.z), f2bf(v1.w)};
                    *(ushort4*)&At[row * 72 + c8 * 8] = lo;
                    *(ushort4*)&At[row * 72 + c8 * 8 + 4] = hi;
                } else {
                    ushort4 z = {0, 0, 0, 0};
                    *(ushort4*)&At[row * 72 + c8 * 8] = z;
                    *(ushort4*)&At[row * 72 + c8 * 8 + 4] = z;
                }
            } else {
                float4 av;
                if (rowg < NN) {
                    av = *(const float4*)((const u16*)A + (size_t)rowg * 256 + kb + c8 * 8);
                } else {
                    av = make_float4(0.f, 0.f, 0.f, 0.f);
                }
                *(float4*)&At[row * 72 + c8 * 8] = av;
            }
            float4 bv = *(const float4*)(BT + (size_t)(n0 + row) * 256 + kb + c8 * 8);
            *(float4*)&Bt[row * 72 + c8 * 8] = bv;
        }
        __syncthreads();
#pragma unroll
        for (int ks = 0; ks < 2; ++ks) {
            short8 af[4], bf[4];
#pragma unroll
            for (int i = 0; i < 4; ++i)
                af[i] = *(const short8*)&At[(wr + i * 16 + cl) * 72 + ks * 32 + q * 8];
#pragma unroll
            for (int j = 0; j < 4; ++j)
                bf[j] = *(const short8*)&Bt[(wc + j * 16 + cl) * 72 + ks * 32 + q * 8];
#pragma unroll
            for (int i = 0; i < 4; ++i)
#pragma unroll
                for (int j = 0; j < 4; ++j)
                    acc[i][j] = __builtin_amdgcn_mfma_f32_16x16x32_bf16(af[i], bf[j], acc[i][j], 0, 0, 0);
        }
        __syncthreads();
    }
#pragma unroll
    for (int i = 0; i < 4; ++i)
#pragma unroll
        for (int j = 0; j < 4; ++j)
#pragma unroll
            for (int r = 0; r < 4; ++r) {
                int mrow = m0 + wr + i * 16 + q * 4 + r;
                if (mrow < NN)
                    C[(size_t)mrow * 256 + n0 + wc + j * 16 + cl] = f2bf(acc[i][j][r]);
            }
}

// ---- layer-1 aggregation: SINGLE PASS no-max softmax ----
// scores ~N(0,2); clamp [-60,60] guards exp overflow/all-zero denom.
__global__ void k_agg1(const int* __restrict__ rowptr, const int* __restrict__ csrc,
                       const float* __restrict__ el, const float* __restrict__ er,
                       const u16* __restrict__ fs, const void* __restrict__ h_in,
                       u16* __restrict__ h1, const int* __restrict__ mode) {
    bool f32m = (*mode) != 0;
    int wave = threadIdx.x >> 6, lane = threadIdx.x & 63;
    int node = blockIdx.x * 4 + wave;
    int beg = rowptr[node], end = rowptr[node + 1];
    int head = lane >> 4;
    float erh = er[node * 4 + head];
    float a0 = 0.f, a1 = 0.f, a2 = 0.f, a3 = 0.f, ll = 0.f;
#pragma unroll 2
    for (int p = beg; p < end; ++p) {
        int s = csrc[p];
        float e = el[s * 4 + head] + erh;
        e = e > 0.f ? e : 0.2f * e;
        e = fminf(fmaxf(e, -60.f), 60.f);
        float pw = __expf(e);
        ushort4 fv = *(const ushort4*)(fs + (size_t)s * 256 + lane * 4);
        ll += pw;
        a0 += pw * bf2f(fv.x);
        a1 += pw * bf2f(fv.y);
        a2 += pw * bf2f(fv.z);
        a3 += pw * bf2f(fv.w);
    }
    float rinv = 1.f / ll;
    float res[4];
    load4(h_in, (size_t)node * 64 + lane, f32m, res);
    float v0 = a0 * rinv + res[0], v1 = a1 * rinv + res[1];
    float v2 = a2 * rinv + res[2], v3 = a3 * rinv + res[3];
    ushort4 o;
    o.x = f2bf(v0 > 0.f ? v0 : __expf(v0) - 1.f);
    o.y = f2bf(v1 > 0.f ? v1 : __expf(v1) - 1.f);
    o.z = f2bf(v2 > 0.f ? v2 : __expf(v2) - 1.f);
    o.w = f2bf(v3 > 0.f ? v3 : __expf(v3) - 1.f);
    ((ushort4*)h1)[(size_t)node * 64 + lane] = o;
}

// ---- layer-2 aggregation: SINGLE PASS + residual + head-mean ----
// c2 layout: [node][256]: cols 0..127 = fs2 (h*32+d), cols 128..255 = res2
__global__ void k_agg2(const int* __restrict__ rowptr, const int* __restrict__ csrc,
                       const float* __restrict__ el, const float* __restrict__ er,
                       const u16* __restrict__ c2, void* __restrict__ out,
                       const int* __restrict__ mode) {
    bool f32m = (*mode) != 0;
    int wave = threadIdx.x >> 6, lane = threadIdx.x & 63;
    int node = blockIdx.x * 4 + wave;
    int beg = rowptr[node], end = rowptr[node + 1];
    int head = lane >> 4;
    float erh = er[node * 4 + head];
    float a0 = 0.f, a1 = 0.f, ll = 0.f;
#pragma unroll 2
    for (int p = beg; p < end; ++p) {
        int s = csrc[p];
        float e = el[s * 4 + head] + erh;
        e = e > 0.f ? e : 0.2f * e;
        e = fminf(fmaxf(e, -60.f), 60.f);
        float pw = __expf(e);
        ushort2 fv = *(const ushort2*)(c2 + (size_t)s * 256 + lane * 2);
        ll += pw;
        a0 += pw * bf2f(fv.x);
        a1 += pw * bf2f(fv.y);
    }
    float rinv = 1.f / ll;
    ushort2 rv = *(const ushort2*)(c2 + (size_t)node * 256 + 128 + lane * 2);
    float o0 = a0 * rinv + bf2f(rv.x);
    float o1 = a1 * rinv + bf2f(rv.y);
    o0 += __shfl_xor(o0, 16, 64); o0 += __shfl_xor(o0, 32, 64);
    o1 += __shfl_xor(o1, 16, 64); o1 += __shfl_xor(o1, 32, 64);
    if (lane < 16) {
        float v0 = 0.25f * o0, v1 = 0.25f * o1;
        size_t oi = (size_t)node * 32 + lane * 2;
        if (f32m) {
            ((float*)out)[oi] = v0;
            ((float*)out)[oi + 1] = v1;
        } else {
            ushort2 ov = {f2bf(v0), f2bf(v1)};
            *(ushort2*)((u16*)out + oi) = ov;
        }
    }
}

extern "C" void kernel_launch(void* const* d_in, const int* in_sizes, int n_in,
                              void* d_out, int out_size, void* d_ws, size_t ws_size,
                              hipStream_t stream) {
    int ih = 0, isrc = 1, idst = 2, iW1s = 3, iW1d = 4, ial1 = 5, iar1 = 6,
        iW2s = 7, iW2d = 8, ial2 = 9, iar2 = 10, iWres = 11;
    if (n_in >= 12 && in_sizes[0] != 12800000) {
        iW1d = 0; iW1s = 1; iW2d = 2; iW2s = 3; iWres = 4; ial1 = 5; ial2 = 6;
        iar1 = 7; iar2 = 8; idst = 9; ih = 10; isrc = 11;
    }
    const void* h     = d_in[ih];
    const int* src    = (const int*)d_in[isrc];
    const int* dst    = (const int*)d_in[idst];
    const void* W1s   = d_in[iW1s];
    const void* W1d   = d_in[iW1d];
    const void* al1   = d_in[ial1];
    const void* ar1   = d_in[iar1];
    const void* W2s   = d_in[iW2s];
    const void* W2d   = d_in[iW2d];
    const void* al2   = d_in[ial2];
    const void* ar2   = d_in[iar2];
    const void* Wres2 = d_in[iWres];

    char* w = (char*)d_ws;
    size_t off = 0;
    auto alloc = [&](size_t bytes) -> void* {
        void* p = w + off;
        off += (bytes + 255) & ~(size_t)255;
        return p;
    };
    int* mode   = (int*)alloc(256);
    float* wl1 = (float*)alloc(256 * 4 * 4);
    float* wr1 = (float*)alloc(256 * 4 * 4);
    float* wl2 = (float*)alloc(256 * 4 * 4);
    float* wr2 = (float*)alloc(256 * 4 * 4);
    int* deg    = (int*)alloc(NN * 4);
    int* cursor = (int*)alloc(NN * 4);
    int* rowptr = (int*)alloc((NN + 1) * 4);
    int* bsum   = (int*)alloc(NBLK_SCAN * 4);
    int* boff   = (int*)alloc(NBLK_SCAN * 4);
    int* csrc   = (int*)alloc((size_t)EE * 4);
    float* el1  = (float*)alloc((size_t)NN * 4 * 4);
    float* er1  = (float*)alloc((size_t)NN * 4 * 4);
    u16* BT1    = (u16*)alloc(256 * 256 * 2);
    u16* BT2    = (u16*)alloc(256 * 256 * 2);
    u16* fs1    = (u16*)alloc((size_t)NN * 256 * 2);   // 25.6 MB
    u16* h1     = (u16*)alloc((size_t)NN * 256 * 2);   // 25.6 MB
    // stream-ordered aliases:
    float* el2 = el1;
    float* er2 = er1;
    u16* c2    = fs1;   // fs1 dead after k_agg1; c2 = [fs2 | res2]

    hipMemsetAsync(deg, 0, NN * 4, stream);

    k_detect<<<1, 256, 0, stream>>>((const u16*)h, mode);
    k_prep<<<528 + (EE + 255) / 256, 256, 0, stream>>>(
        W1s, al1, W1d, ar1, W2s, al2, W2d, ar2, Wres2, dst,
        BT1, BT2, wl1, wr1, wl2, wr2, deg, mode);
    k_scan1<<<NBLK_SCAN, 512, 0, stream>>>(deg, rowptr, bsum);
    k_scan2<<<1, 128, 0, stream>>>(bsum, boff);
    k_scan3<<<(NN + 255) / 256, 256, 0, stream>>>(rowptr, boff, cursor);
    k_scatter<<<(EE + 255) / 256, 256, 0, stream>>>(src, dst, cursor, csrc);

    // layer 1
    k_eler<<<NN / 4, 256, 0, stream>>>(h, 1, wl1, wr1, el1, er1, mode);
    k_gemm_mfma<<<391 * 2, 256, 0, stream>>>(h, 1, BT1, fs1, mode);
    k_agg1<<<NN / 4, 256, 0, stream>>>(rowptr, csrc, el1, er1, fs1, h, h1, mode);

    // layer 2 (one fused GEMM: [W2s | Wres2])
    k_eler<<<NN / 4, 256, 0, stream>>>(h1, 0, wl2, wr2, el2, er2, mode);
    k_gemm_mfma<<<391 * 2, 256, 0, stream>>>(h1, 0, BT2, c2, mode);
    k_agg2<<<NN / 4, 256, 0, stream>>>(rowptr, csrc, el2, er2, c2, d_out, mode);
}